// Round 1
// baseline (2176.941 us; speedup 1.0000x reference)
//
#include <hip/hip_runtime.h>
#include <math.h>

#define Nn 16384
#define Dd 128
#define Kk 32
#define ITILE 64
#define JTILE 256
#define DCHUNK 16
#define NCHUNK ((Nn / JTILE) * (Dd / DCHUNK))  // 512
#define LCAP 64

// ---------------------------------------------------------------- sqn ------
__global__ __launch_bounds__(256) void sqn_kernel(const float* __restrict__ X,
                                                  float* __restrict__ sqn) {
    const int i = blockIdx.x * 4 + (threadIdx.x >> 6);
    const int lane = threadIdx.x & 63;
    float2 v = *(const float2*)(X + (size_t)i * Dd + lane * 2);
    float s = fmaf(v.x, v.x, v.y * v.y);
#pragma unroll
    for (int o = 32; o > 0; o >>= 1) s += __shfl_down(s, o);
    if (lane == 0) sqn[i] = s;
}

// ---------------------------------------------------------------- knn ------
// 256 blocks x 256 threads. Block owns 64 i-rows. j tiled by 256, d by 16.
// Per-thread 8i x 8j register tile. Per-row top-32 via LDS reservoir (cap 64)
// with rank-select compaction and pend-retry on overflow.
__global__ __launch_bounds__(256) void knn_kernel(const float* __restrict__ X,
                                                  const float* __restrict__ sqn,
                                                  int* __restrict__ idx_out) {
    __shared__ float XjT[DCHUNK][JTILE];   // 16 KB  (d-major, transposed)
    __shared__ float XiT[DCHUNK][ITILE];   // 4 KB
    __shared__ float listv[ITILE][LCAP];   // 16 KB
    __shared__ int   listj[ITILE][LCAP];   // 16 KB
    __shared__ float thr[ITILE];
    __shared__ int   cnt[ITILE];
    __shared__ int   pendFlag;

    const int tid  = threadIdx.x;
    const int lane = tid & 63;
    const int wave = tid >> 6;
    const int jg   = tid & 31;   // j-group: 8 consecutive j
    const int ig   = tid >> 5;   // i-group: 8 consecutive i
    const int i0   = blockIdx.x * ITILE;

    for (int r = tid; r < ITILE; r += 256) { thr[r] = INFINITY; cnt[r] = 0; }
    __syncthreads();

    float acc[8][8];
    float4 vj0, vj1, vj2, vj3, vi;

    // prefetch chunk 0
    {
        const float4* sj = (const float4*)(X + (size_t)tid * Dd);
        vj0 = sj[0]; vj1 = sj[1]; vj2 = sj[2]; vj3 = sj[3];
        vi = *(const float4*)(X + (size_t)(i0 + (tid & 63)) * Dd + (tid >> 6) * 4);
    }

    for (int c = 0; c < NCHUNK; c++) {
        const int tile = c >> 3;
        const int dsub = c & 7;
        if (dsub == 0) {
#pragma unroll
            for (int a = 0; a < 8; a++)
#pragma unroll
                for (int b = 0; b < 8; b++) acc[a][b] = 0.f;
        }
        __syncthreads();
        // stage prefetched regs -> LDS (transpose)
        XjT[0][tid] = vj0.x;  XjT[1][tid] = vj0.y;  XjT[2][tid] = vj0.z;  XjT[3][tid] = vj0.w;
        XjT[4][tid] = vj1.x;  XjT[5][tid] = vj1.y;  XjT[6][tid] = vj1.z;  XjT[7][tid] = vj1.w;
        XjT[8][tid] = vj2.x;  XjT[9][tid] = vj2.y;  XjT[10][tid] = vj2.z; XjT[11][tid] = vj2.w;
        XjT[12][tid] = vj3.x; XjT[13][tid] = vj3.y; XjT[14][tid] = vj3.z; XjT[15][tid] = vj3.w;
        {
            const int row = tid & 63, dq = tid >> 6;
            XiT[dq * 4 + 0][row] = vi.x; XiT[dq * 4 + 1][row] = vi.y;
            XiT[dq * 4 + 2][row] = vi.z; XiT[dq * 4 + 3][row] = vi.w;
        }
        __syncthreads();
        // prefetch next chunk (overlaps FMA loop below)
        if (c + 1 < NCHUNK) {
            const int nt = (c + 1) >> 3, nd = ((c + 1) & 7) * DCHUNK;
            const float4* sj = (const float4*)(X + (size_t)(nt * JTILE + tid) * Dd + nd);
            vj0 = sj[0]; vj1 = sj[1]; vj2 = sj[2]; vj3 = sj[3];
            vi = *(const float4*)(X + (size_t)(i0 + (tid & 63)) * Dd + nd + (tid >> 6) * 4);
        }
        // FMA: 16 d-steps x 64 accs
#pragma unroll
        for (int d = 0; d < DCHUNK; d++) {
            float a[8], b[8];
            *(float4*)&a[0] = *(const float4*)&XiT[d][ig * 8];
            *(float4*)&a[4] = *(const float4*)&XiT[d][ig * 8 + 4];
            *(float4*)&b[0] = *(const float4*)&XjT[d][jg * 8];
            *(float4*)&b[4] = *(const float4*)&XjT[d][jg * 8 + 4];
#pragma unroll
            for (int ii = 0; ii < 8; ii++)
#pragma unroll
                for (int jj = 0; jj < 8; jj++)
                    acc[ii][jj] = fmaf(a[ii], b[jj], acc[ii][jj]);
        }

        if (dsub == 7) {
            // ---- candidate phase: rank key r = sqn[j] - 2*dot (sqn[i] const/row)
            const int jbase = tile * JTILE + jg * 8;
            float sj[8];
#pragma unroll
            for (int jj = 0; jj < 8; jj++) sj[jj] = sqn[jbase + jj];
            unsigned long long pend = 0ull;
#pragma unroll
            for (int ii = 0; ii < 8; ii++) {
                const float t = thr[ig * 8 + ii];
#pragma unroll
                for (int jj = 0; jj < 8; jj++) {
                    const float rv = fmaf(-2.f, acc[ii][jj], sj[jj]);
                    acc[ii][jj] = rv;  // reuse acc as candidate storage
                    if (rv < t) pend |= (1ull << (ii * 8 + jj));
                }
            }
            while (true) {
                __syncthreads();
                if (tid == 0) pendFlag = 0;
                __syncthreads();
                if (pend) {
#pragma unroll
                    for (int ii = 0; ii < 8; ii++) {
#pragma unroll
                        for (int jj = 0; jj < 8; jj++) {
                            const unsigned long long bit = 1ull << (ii * 8 + jj);
                            if (pend & bit) {
                                const int il = ig * 8 + ii;
                                const float rv = acc[ii][jj];
                                if (rv < thr[il]) {
                                    const int pos = atomicAdd(&cnt[il], 1);
                                    if (pos < LCAP) {
                                        listv[il][pos] = rv;
                                        listj[il][pos] = jbase + jj;
                                        pend &= ~bit;
                                    }  // else keep pending: retry after compaction
                                } else {
                                    pend &= ~bit;
                                }
                            }
                        }
                    }
                    if (pend) pendFlag = 1;
                }
                __syncthreads();
                // compaction: rank-select 32 smallest of 64, update threshold
                for (int r = wave; r < ITILE; r += 4) {
                    if (cnt[r] >= LCAP) {
                        const float v = listv[r][lane];
                        const int j = listj[r][lane];
                        int rk = 0;
#pragma unroll 8
                        for (int s = 0; s < 64; s++) {
                            const float ov = __shfl(v, s);
                            rk += (ov < v || (ov == v && s < lane)) ? 1 : 0;
                        }
                        if (rk < Kk) { listv[r][rk] = v; listj[r][rk] = j; }
                        if (rk == Kk - 1) { thr[r] = v; cnt[r] = Kk; }
                    }
                }
                __syncthreads();
                if (pendFlag == 0) break;
            }
        }
    }
    // ---- final top-32 select per row (order irrelevant: max-pool is set-invariant)
    for (int r = wave; r < ITILE; r += 4) {
        const int n = min(cnt[r], LCAP);
        const float v = (lane < n) ? listv[r][lane] : INFINITY;
        const int j = (lane < n) ? listj[r][lane] : 0;
        int rk = 0;
#pragma unroll 8
        for (int s = 0; s < 64; s++) {
            const float ov = __shfl(v, s);
            rk += (ov < v || (ov == v && s < lane)) ? 1 : 0;
        }
        if (rk < Kk) idx_out[(size_t)(i0 + r) * Kk + rk] = j;
    }
}

// ------------------------------------------------- P = X@(W1a-W1b)+b1, Q = X@W1b
__global__ __launch_bounds__(256) void pq_kernel(const float* __restrict__ X,
                                                 const float* __restrict__ W1,
                                                 const float* __restrict__ b1,
                                                 float* __restrict__ P,
                                                 float* __restrict__ Q) {
    __shared__ float xrow[16][Dd];  // 8 KB
    const int i0 = blockIdx.x * 16;
    for (int t = threadIdx.x; t < 16 * Dd / 4; t += 256)
        ((float4*)&xrow[0][0])[t] = ((const float4*)(X + (size_t)i0 * Dd))[t];
    __syncthreads();
    const int cc = threadIdx.x & 127;
    const int mat = threadIdx.x >> 7;  // 0: P, 1: Q
    float acc[16];
#pragma unroll
    for (int r = 0; r < 16; r++) acc[r] = 0.f;
    for (int d = 0; d < Dd; d++) {
        float w;
        if (mat == 0) w = W1[d * 128 + cc] - W1[(128 + d) * 128 + cc];
        else          w = W1[(128 + d) * 128 + cc];
#pragma unroll
        for (int r = 0; r < 16; r++) acc[r] = fmaf(xrow[r][d], w, acc[r]);
    }
    if (mat == 0) {
        const float b = b1[cc];
#pragma unroll
        for (int r = 0; r < 16; r++) P[(size_t)(i0 + r) * 128 + cc] = acc[r] + b;
    } else {
#pragma unroll
        for (int r = 0; r < 16; r++) Q[(size_t)(i0 + r) * 128 + cc] = acc[r];
    }
}

// ------------------------------------------- h1 = relu(P + max_k Q[idx]) ----
__global__ __launch_bounds__(128) void h1_kernel(const float* __restrict__ P,
                                                 const float* __restrict__ Q,
                                                 const int* __restrict__ idx,
                                                 float* __restrict__ h1) {
    const int i = blockIdx.x;
    const int c = threadIdx.x;
    __shared__ int jb[Kk];
    if (threadIdx.x < Kk) jb[threadIdx.x] = idx[(size_t)i * Kk + threadIdx.x];
    __syncthreads();
    float m = -INFINITY;
#pragma unroll
    for (int k = 0; k < Kk; k++) m = fmaxf(m, Q[(size_t)jb[k] * 128 + c]);
    h1[(size_t)i * 128 + c] = fmaxf(P[(size_t)i * 128 + c] + m, 0.f);
}

// --------------------------- P2 = h1@(W2a-W2b)+b2, Q2 = h1@W2b (C=10) -------
__global__ __launch_bounds__(256) void pq2_kernel(const float* __restrict__ h1,
                                                  const float* __restrict__ W2,
                                                  const float* __restrict__ b2,
                                                  float* __restrict__ P2,
                                                  float* __restrict__ Q2) {
    const int lane = threadIdx.x & 63;
    const int wave = threadIdx.x >> 6;
#pragma unroll
    for (int rr = 0; rr < 4; rr++) {
        const int i = blockIdx.x * 16 + wave * 4 + rr;
        const float2 h = *(const float2*)(h1 + (size_t)i * 128 + lane * 2);
#pragma unroll
        for (int c = 0; c < 10; c++) {
            const float wt0 = W2[(2 * lane) * 10 + c];
            const float wt1 = W2[(2 * lane + 1) * 10 + c];
            const float wb0 = W2[(128 + 2 * lane) * 10 + c];
            const float wb1 = W2[(129 + 2 * lane) * 10 + c];
            float pa = fmaf(h.x, wt0, h.y * wt1);
            float pb = fmaf(h.x, wb0, h.y * wb1);
#pragma unroll
            for (int o = 32; o > 0; o >>= 1) {
                pa += __shfl_down(pa, o);
                pb += __shfl_down(pb, o);
            }
            if (lane == 0) {
                P2[(size_t)i * 10 + c] = pa - pb + b2[c];
                Q2[(size_t)i * 10 + c] = pb;
            }
        }
    }
}

// ---------------------------------- out = P2 + max_k Q2[idx] (no relu) ------
__global__ __launch_bounds__(256) void out_kernel(const float* __restrict__ P2,
                                                  const float* __restrict__ Q2,
                                                  const int* __restrict__ idx,
                                                  float* __restrict__ out) {
    const int g = blockIdx.x * 256 + threadIdx.x;
    const int i = g >> 4;
    const int c = g & 15;
    if (c >= 10) return;
    const int* jr = idx + (size_t)i * Kk;
    float m = -INFINITY;
#pragma unroll
    for (int k = 0; k < Kk; k++) m = fmaxf(m, Q2[(size_t)jr[k] * 10 + c]);
    out[(size_t)i * 10 + c] = P2[(size_t)i * 10 + c] + m;
}

extern "C" void kernel_launch(void* const* d_in, const int* in_sizes, int n_in,
                              void* d_out, int out_size, void* d_ws, size_t ws_size,
                              hipStream_t stream) {
    const float* X  = (const float*)d_in[0];
    const float* W1 = (const float*)d_in[1];
    const float* b1 = (const float*)d_in[2];
    const float* W2 = (const float*)d_in[3];
    const float* b2 = (const float*)d_in[4];
    float* out = (float*)d_out;

    char* ws = (char*)d_ws;
    float* sqn = (float*)ws;                          // 64 KB
    int*   idx = (int*)(ws + (1 << 16));              // 2 MB
    float* P   = (float*)(ws + (1 << 16) + (1 << 21));
    float* Q   = P + (size_t)Nn * 128;                // 8 MB each
    float* h1  = Q + (size_t)Nn * 128;
    float* P2  = h1 + (size_t)Nn * 128;               // 640 KB each
    float* Q2  = P2 + (size_t)Nn * 10;

    sqn_kernel<<<Nn / 4, 256, 0, stream>>>(X, sqn);
    pq_kernel<<<Nn / 16, 256, 0, stream>>>(X, W1, b1, P, Q);
    knn_kernel<<<Nn / ITILE, 256, 0, stream>>>(X, sqn, idx);
    h1_kernel<<<Nn, 128, 0, stream>>>(P, Q, idx, h1);
    pq2_kernel<<<Nn / 16, 256, 0, stream>>>(h1, W2, b2, P2, Q2);
    out_kernel<<<Nn * 16 / 256, 256, 0, stream>>>(P2, Q2, idx, out);
}

// Round 3
// 1902.238 us; speedup vs baseline: 1.1444x; 1.1444x over previous
//
#include <hip/hip_runtime.h>
#include <math.h>

#define Nn 16384
#define Dd 128
#define Kk 32
#define ITILE 64
#define JTILE 128
#define LDK 136          // padded LDS row pitch in bf16 elems (272 B)
#define LCAP 64
#define NJT (Nn / JTILE) // 128
#define BAND 0.05f       // guard band >> 2x max split-bf16 d2 error (~1e-3 6-sigma)

typedef unsigned short u16;
typedef short short8 __attribute__((ext_vector_type(8)));
typedef float f32x4 __attribute__((ext_vector_type(4)));
struct __attribute__((aligned(8))) u16x4 { u16 x, y, z, w; };

__device__ __forceinline__ u16 f2bf(float x) {
    unsigned u = __float_as_uint(x);
    unsigned r = u + 0x7FFFu + ((u >> 16) & 1u);   // RN-even
    return (u16)(r >> 16);
}
__device__ __forceinline__ float bf2f(u16 h) { return __uint_as_float(((unsigned)h) << 16); }

// ----------------------------------------------------- split bf16 convert --
__global__ __launch_bounds__(256) void cvt_kernel(const float* __restrict__ X,
                                                  u16* __restrict__ hi,
                                                  u16* __restrict__ lo) {
    const int g = blockIdx.x * 256 + threadIdx.x;   // one float4 per thread
    const float4 v = ((const float4*)X)[g];
    u16x4 h, l;
    h.x = f2bf(v.x); l.x = f2bf(v.x - bf2f(h.x));
    h.y = f2bf(v.y); l.y = f2bf(v.y - bf2f(h.y));
    h.z = f2bf(v.z); l.z = f2bf(v.z - bf2f(h.z));
    h.w = f2bf(v.w); l.w = f2bf(v.w - bf2f(h.w));
    ((u16x4*)hi)[g] = h;
    ((u16x4*)lo)[g] = l;
}

// ---------------------------------------------------------------- sqn ------
__global__ __launch_bounds__(256) void sqn_kernel(const float* __restrict__ X,
                                                  float* __restrict__ sqn) {
    const int i = blockIdx.x * 4 + (threadIdx.x >> 6);
    const int lane = threadIdx.x & 63;
    float2 v = *(const float2*)(X + (size_t)i * Dd + lane * 2);
    float s = fmaf(v.x, v.x, v.y * v.y);
#pragma unroll
    for (int o = 32; o > 0; o >>= 1) s += __shfl_down(s, o);
    if (lane == 0) sqn[i] = s;
}

// ---------------------------------------------------------------- knn ------
// Split-bf16 MFMA sweep as APPROXIMATE filter (band-compacted reservoir keeps
// everything within BAND of the 32nd-smallest), then exact fp32 re-rank of the
// <=64 surviving candidates per row.
__global__ __launch_bounds__(256) void knn_kernel(const float* __restrict__ X,
                                                  const u16* __restrict__ Xhi,
                                                  const u16* __restrict__ Xlo,
                                                  const float* __restrict__ sqn,
                                                  int* __restrict__ idx_out) {
    extern __shared__ char smem[];
    u16* XiH = (u16*)smem;                       // 64*136
    u16* XiL = XiH + 64 * LDK;                   // 64*136
    u16* XjH = XiL + 64 * LDK;                   // 128*136
    u16* XjL = XjH + 128 * LDK;                  // 128*136
    float* listv = (float*)(XjL + 128 * LDK);    // 64*64
    int* listj = (int*)(listv + 64 * LCAP);      // 64*64
    float* sqnS = (float*)(listj + 64 * LCAP);   // 128
    float* thr = sqnS + JTILE;                   // 64
    int* cnt = (int*)(thr + ITILE);              // 64
    int* pendFlag = cnt + ITILE;
    float* Xi32 = (float*)XjH;                   // reused AFTER sweep (32 KB)

    const int tid = threadIdx.x;
    const int wave = tid >> 6, lane = tid & 63;
    const int quad = lane >> 4, n16 = lane & 15;
    const int i0 = blockIdx.x * ITILE;

    for (int r = tid; r < ITILE; r += 256) { thr[r] = INFINITY; cnt[r] = 0; }

    // ---- stage Xi (64 rows, full K) hi+lo
    {
        const int r = tid >> 2, q = (tid & 3) * 32;
        const u16* sH = Xhi + (size_t)(i0 + r) * Dd + q;
        const u16* sL = Xlo + (size_t)(i0 + r) * Dd + q;
        u16* dH = XiH + r * LDK + q;
        u16* dL = XiL + r * LDK + q;
#pragma unroll
        for (int u = 0; u < 4; u++) ((float4*)dH)[u] = ((const float4*)sH)[u];
#pragma unroll
        for (int u = 0; u < 4; u++) ((float4*)dL)[u] = ((const float4*)sL)[u];
    }

    f32x4 acc[8];

    for (int jt = 0; jt < NJT; jt++) {
        const int j0 = jt * JTILE;
        // ---- stage Xj tile (safe: all threads passed prior exit barrier)
        {
            const int r = tid >> 1, hh = (tid & 1) * 64;
            const u16* sH = Xhi + (size_t)(j0 + r) * Dd + hh;
            const u16* sL = Xlo + (size_t)(j0 + r) * Dd + hh;
            u16* dH = XjH + r * LDK + hh;
            u16* dL = XjL + r * LDK + hh;
#pragma unroll
            for (int u = 0; u < 8; u++) ((float4*)dH)[u] = ((const float4*)sH)[u];
#pragma unroll
            for (int u = 0; u < 8; u++) ((float4*)dL)[u] = ((const float4*)sL)[u];
            if (tid < JTILE) sqnS[tid] = sqn[j0 + tid];
        }
        __syncthreads();

        // ---- MFMA: S = Xi . Xj^T  (split: hi*hi + hi*lo + lo*hi)
#pragma unroll
        for (int t = 0; t < 8; t++) acc[t] = (f32x4){0.f, 0.f, 0.f, 0.f};
#pragma unroll
        for (int ks = 0; ks < 4; ks++) {
            const int koff = ks * 32 + quad * 8;
            short8 aH[4], aL[4], bH[2], bL[2];
#pragma unroll
            for (int is = 0; is < 4; is++) {
                aH[is] = *(const short8*)(XiH + (is * 16 + n16) * LDK + koff);
                aL[is] = *(const short8*)(XiL + (is * 16 + n16) * LDK + koff);
            }
#pragma unroll
            for (int js = 0; js < 2; js++) {
                const int jrow = (wave * 2 + js) * 16 + n16;
                bH[js] = *(const short8*)(XjH + jrow * LDK + koff);
                bL[js] = *(const short8*)(XjL + jrow * LDK + koff);
            }
#pragma unroll
            for (int is = 0; is < 4; is++)
#pragma unroll
                for (int js = 0; js < 2; js++) {
                    const int t = is * 2 + js;
                    acc[t] = __builtin_amdgcn_mfma_f32_16x16x32_bf16(aH[is], bH[js], acc[t], 0, 0, 0);
                    acc[t] = __builtin_amdgcn_mfma_f32_16x16x32_bf16(aH[is], bL[js], acc[t], 0, 0, 0);
                    acc[t] = __builtin_amdgcn_mfma_f32_16x16x32_bf16(aL[is], bH[js], acc[t], 0, 0, 0);
                }
        }

        // ---- epilogue: approx rank key rv = sqn[j] - 2*dot
        unsigned pend = 0u;
        float sj[2];
#pragma unroll
        for (int js = 0; js < 2; js++) sj[js] = sqnS[(wave * 2 + js) * 16 + n16];
#pragma unroll
        for (int t = 0; t < 8; t++) {
            const int is = t >> 1, js = t & 1;
#pragma unroll
            for (int r = 0; r < 4; r++) {
                const int il = is * 16 + quad * 4 + r;
                const float rv = fmaf(-2.f, acc[t][r], sj[js]);
                acc[t][r] = rv;
                if (rv < thr[il]) pend |= 1u << (t * 4 + r);
            }
        }

        // ---- reservoir insert + band compaction
        while (true) {
            __syncthreads();
            if (tid == 0) *pendFlag = 0;
            __syncthreads();
            if (pend) {
#pragma unroll
                for (int t = 0; t < 8; t++) {
                    const int is = t >> 1, js = t & 1;
#pragma unroll
                    for (int r = 0; r < 4; r++) {
                        const unsigned bit = 1u << (t * 4 + r);
                        if (pend & bit) {
                            const int il = is * 16 + quad * 4 + r;
                            const float rv = acc[t][r];
                            if (rv < thr[il]) {
                                const int pos = atomicAdd(&cnt[il], 1);
                                if (pos < LCAP) {
                                    listv[il * LCAP + pos] = rv;
                                    listj[il * LCAP + pos] = j0 + (wave * 2 + js) * 16 + n16;
                                    pend &= ~bit;
                                }  // else retry after compaction
                            } else {
                                pend &= ~bit;
                            }
                        }
                    }
                }
                if (pend) *pendFlag = 1;
            }
            __syncthreads();
            // compaction: keep rank<32 PLUS everything within BAND of v32
            for (int rr = wave; rr < ITILE; rr += 4) {
                if (cnt[rr] >= LCAP) {
                    const float v = listv[rr * LCAP + lane];
                    const int jj = listj[rr * LCAP + lane];
                    int rk = 0;
#pragma unroll 8
                    for (int s = 0; s < 64; s++) {
                        const float ov = __shfl(v, s);
                        rk += (ov < v || (ov == v && s < lane)) ? 1 : 0;
                    }
                    const unsigned long long m31 = __ballot(rk == Kk - 1);
                    const float v32 = __shfl(v, (int)(__ffsll((unsigned long long)m31) - 1));
                    int m = __popcll(__ballot(v < v32 + BAND));
                    m = min(m, 56);   // always leave >=8 free slots (progress)
                    if (rk < m) { listv[rr * LCAP + rk] = v; listj[rr * LCAP + rk] = jj; }
                    if (lane == 0) { thr[rr] = v32 + BAND; cnt[rr] = m; }
                }
            }
            __syncthreads();
            if (*pendFlag == 0) break;
        }
    }

    // ================= exact fp32 re-rank of surviving candidates ==========
    __syncthreads();
    {   // stage Xi fp32 into dead Xj region
        const int r = tid >> 2, q = (tid & 3) * 32;
        const float* s = X + (size_t)(i0 + r) * Dd + q;
        float* dst = Xi32 + r * Dd + q;
#pragma unroll
        for (int u = 0; u < 8; u++) ((float4*)dst)[u] = ((const float4*)s)[u];
    }
    __syncthreads();
    for (int rr = wave; rr < ITILE; rr += 4) {
        const int n = min(cnt[rr], LCAP);
        const int jj = (lane < n) ? listj[rr * LCAP + lane] : -1;
        float rv = INFINITY;
        if (jj >= 0) {
            const float* xj = X + (size_t)jj * Dd;
            const float* xi = Xi32 + rr * Dd;
            float s0 = 0.f, s1 = 0.f, s2 = 0.f, s3 = 0.f;
#pragma unroll
            for (int d = 0; d < Dd; d += 4) {
                const float4 a = *(const float4*)(xi + d);
                const float4 b = *(const float4*)(xj + d);
                s0 = fmaf(a.x, b.x, s0); s1 = fmaf(a.y, b.y, s1);
                s2 = fmaf(a.z, b.z, s2); s3 = fmaf(a.w, b.w, s3);
            }
            rv = fmaf(-2.f, (s0 + s1) + (s2 + s3), sqn[jj]);
        }
        int rk = 0;
#pragma unroll 8
        for (int s = 0; s < 64; s++) {
            const float ov = __shfl(rv, s);
            rk += (ov < rv || (ov == rv && s < lane)) ? 1 : 0;
        }
        if (rk < Kk) idx_out[(size_t)(i0 + rr) * Kk + rk] = jj;
    }
}

// ------------------------------------------------- P = X@(W1a-W1b)+b1, Q = X@W1b
__global__ __launch_bounds__(256) void pq_kernel(const float* __restrict__ X,
                                                 const float* __restrict__ W1,
                                                 const float* __restrict__ b1,
                                                 float* __restrict__ P,
                                                 float* __restrict__ Q) {
    __shared__ float xrow[16][Dd];
    const int i0 = blockIdx.x * 16;
    for (int t = threadIdx.x; t < 16 * Dd / 4; t += 256)
        ((float4*)&xrow[0][0])[t] = ((const float4*)(X + (size_t)i0 * Dd))[t];
    __syncthreads();
    const int cc = threadIdx.x & 127;
    const int mat = threadIdx.x >> 7;
    float acc[16];
#pragma unroll
    for (int r = 0; r < 16; r++) acc[r] = 0.f;
    for (int d = 0; d < Dd; d++) {
        float w;
        if (mat == 0) w = W1[d * 128 + cc] - W1[(128 + d) * 128 + cc];
        else          w = W1[(128 + d) * 128 + cc];
#pragma unroll
        for (int r = 0; r < 16; r++) acc[r] = fmaf(xrow[r][d], w, acc[r]);
    }
    if (mat == 0) {
        const float b = b1[cc];
#pragma unroll
        for (int r = 0; r < 16; r++) P[(size_t)(i0 + r) * 128 + cc] = acc[r] + b;
    } else {
#pragma unroll
        for (int r = 0; r < 16; r++) Q[(size_t)(i0 + r) * 128 + cc] = acc[r];
    }
}

// ------------------------------------------- h1 = relu(P + max_k Q[idx]) ----
__global__ __launch_bounds__(128) void h1_kernel(const float* __restrict__ P,
                                                 const float* __restrict__ Q,
                                                 const int* __restrict__ idx,
                                                 float* __restrict__ h1) {
    const int i = blockIdx.x;
    const int c = threadIdx.x;
    __shared__ int jb[Kk];
    if (threadIdx.x < Kk) jb[threadIdx.x] = idx[(size_t)i * Kk + threadIdx.x];
    __syncthreads();
    float m = -INFINITY;
#pragma unroll
    for (int k = 0; k < Kk; k++) m = fmaxf(m, Q[(size_t)jb[k] * 128 + c]);
    h1[(size_t)i * 128 + c] = fmaxf(P[(size_t)i * 128 + c] + m, 0.f);
}

// --------------------------- P2 = h1@(W2a-W2b)+b2, Q2 = h1@W2b (C=10) -------
__global__ __launch_bounds__(256) void pq2_kernel(const float* __restrict__ h1,
                                                  const float* __restrict__ W2,
                                                  const float* __restrict__ b2,
                                                  float* __restrict__ P2,
                                                  float* __restrict__ Q2) {
    const int lane = threadIdx.x & 63;
    const int wave = threadIdx.x >> 6;
#pragma unroll
    for (int rr = 0; rr < 4; rr++) {
        const int i = blockIdx.x * 16 + wave * 4 + rr;
        const float2 h = *(const float2*)(h1 + (size_t)i * 128 + lane * 2);
#pragma unroll
        for (int c = 0; c < 10; c++) {
            const float wt0 = W2[(2 * lane) * 10 + c];
            const float wt1 = W2[(2 * lane + 1) * 10 + c];
            const float wb0 = W2[(128 + 2 * lane) * 10 + c];
            const float wb1 = W2[(129 + 2 * lane) * 10 + c];
            float pa = fmaf(h.x, wt0, h.y * wt1);
            float pb = fmaf(h.x, wb0, h.y * wb1);
#pragma unroll
            for (int o = 32; o > 0; o >>= 1) {
                pa += __shfl_down(pa, o);
                pb += __shfl_down(pb, o);
            }
            if (lane == 0) {
                P2[(size_t)i * 10 + c] = pa - pb + b2[c];
                Q2[(size_t)i * 10 + c] = pb;
            }
        }
    }
}

// ---------------------------------- out = P2 + max_k Q2[idx] (no relu) ------
__global__ __launch_bounds__(256) void out_kernel(const float* __restrict__ P2,
                                                  const float* __restrict__ Q2,
                                                  const int* __restrict__ idx,
                                                  float* __restrict__ out) {
    const int g = blockIdx.x * 256 + threadIdx.x;
    const int i = g >> 4;
    const int c = g & 15;
    if (c >= 10) return;
    const int* jr = idx + (size_t)i * Kk;
    float m = -INFINITY;
#pragma unroll
    for (int k = 0; k < Kk; k++) m = fmaxf(m, Q2[(size_t)jr[k] * 10 + c]);
    out[(size_t)i * 10 + c] = P2[(size_t)i * 10 + c] + m;
}

extern "C" void kernel_launch(void* const* d_in, const int* in_sizes, int n_in,
                              void* d_out, int out_size, void* d_ws, size_t ws_size,
                              hipStream_t stream) {
    const float* X  = (const float*)d_in[0];
    const float* W1 = (const float*)d_in[1];
    const float* b1 = (const float*)d_in[2];
    const float* W2 = (const float*)d_in[3];
    const float* b2 = (const float*)d_in[4];
    float* out = (float*)d_out;

    char* ws = (char*)d_ws;
    float* sqn = (float*)ws;                                  // 64 KB
    int*   idx = (int*)(ws + (1 << 16));                      // 2 MB
    u16*   Xhi = (u16*)(ws + 2162688);                        // 4 MB
    u16*   Xlo = (u16*)(ws + 6356992);                        // 4 MB
    float* P   = (float*)(ws + 10551296);                     // 8 MB
    float* Q   = P + (size_t)Nn * 128;                        // 8 MB
    float* h1  = Q + (size_t)Nn * 128;                        // 8 MB
    float* P2  = h1 + (size_t)Nn * 128;                       // 640 KB
    float* Q2  = P2 + (size_t)Nn * 10;                        // 640 KB

    // dynamic LDS: (64+64+128+128)*136 u16 + reservoir + small = 138,244 B
    const int smemBytes = (384 * LDK) * 2 + 64 * LCAP * 8 + JTILE * 4 + ITILE * 8 + 8;
    hipFuncSetAttribute((const void*)knn_kernel,
                        hipFuncAttributeMaxDynamicSharedMemorySize, smemBytes);

    cvt_kernel<<<Nn * Dd / 4 / 256, 256, 0, stream>>>(X, Xhi, Xlo);
    sqn_kernel<<<Nn / 4, 256, 0, stream>>>(X, sqn);
    knn_kernel<<<Nn / ITILE, 256, smemBytes, stream>>>(X, Xhi, Xlo, sqn, idx);
    pq_kernel<<<Nn / 16, 256, 0, stream>>>(X, W1, b1, P, Q);
    h1_kernel<<<Nn, 128, 0, stream>>>(P, Q, idx, h1);
    pq2_kernel<<<Nn / 16, 256, 0, stream>>>(h1, W2, b2, P2, Q2);
    out_kernel<<<Nn * 16 / 256, 256, 0, stream>>>(P2, Q2, idx, out);
}

// Round 4
// 1237.655 us; speedup vs baseline: 1.7589x; 1.5370x over previous
//
#include <hip/hip_runtime.h>
#include <math.h>

#define Nn 16384
#define Dd 128
#define Kk 32
#define ITILE 64
#define JTILE 128
#define LCAP 48
#define KEEP 40          // compaction keep cap; slack LCAP-KEEP=8 guarantees progress
#define BAND 0.5f        // ~16 sigma of hi-only bf16 d2 error (sigma~0.03)
#define NJT (Nn / JTILE) // 128

typedef unsigned short u16;
typedef short short8 __attribute__((ext_vector_type(8)));
typedef float f32x4 __attribute__((ext_vector_type(4)));
struct __attribute__((aligned(8))) u16x4 { u16 x, y, z, w; };

__device__ __forceinline__ u16 f2bf(float x) {
    unsigned u = __float_as_uint(x);
    unsigned r = u + 0x7FFFu + ((u >> 16) & 1u);   // RN-even
    return (u16)(r >> 16);
}

// ------------------------------------------------------- bf16 convert ------
__global__ __launch_bounds__(256) void cvt_kernel(const float* __restrict__ X,
                                                  u16* __restrict__ hi) {
    const int g = blockIdx.x * 256 + threadIdx.x;   // one float4 per thread
    const float4 v = ((const float4*)X)[g];
    u16x4 h;
    h.x = f2bf(v.x); h.y = f2bf(v.y); h.z = f2bf(v.z); h.w = f2bf(v.w);
    ((u16x4*)hi)[g] = h;
}

// ---------------------------------------------------------------- sqn ------
__global__ __launch_bounds__(256) void sqn_kernel(const float* __restrict__ X,
                                                  float* __restrict__ sqn) {
    const int i = blockIdx.x * 4 + (threadIdx.x >> 6);
    const int lane = threadIdx.x & 63;
    float2 v = *(const float2*)(X + (size_t)i * Dd + lane * 2);
    float s = fmaf(v.x, v.x, v.y * v.y);
#pragma unroll
    for (int o = 32; o > 0; o >>= 1) s += __shfl_down(s, o);
    if (lane == 0) sqn[i] = s;
}

// ---------------------------------------------------------------- knn ------
// 256 blocks x 512 threads (8 waves, 2/SIMD). Block owns 64 i-rows; wave w
// owns j-subtile w of each 128-wide j-tile. A-frags live in registers for the
// whole kernel; B-frags are direct dwordx4 global loads (L2-resident),
// register double-buffered. Hot loop has no LDS staging and typically ONE
// barrier (__syncthreads_or) per tile. Approx hi-bf16 filter with banded
// reservoir, then exact fp32 re-rank.
__global__ __launch_bounds__(512, 2) void knn_kernel(const float* __restrict__ X,
                                                     const u16* __restrict__ Xhi,
                                                     const float* __restrict__ sqn,
                                                     int* __restrict__ idx_out) {
    __shared__ float listv[ITILE][LCAP];   // 12 KB
    __shared__ int   listj[ITILE][LCAP];   // 12 KB
    __shared__ float thr[ITILE];
    __shared__ int   cnt[ITILE];
    __shared__ float xi32[ITILE][Dd];      // 32 KB (used only in final re-rank)

    const int tid = threadIdx.x;
    const int wave = tid >> 6, lane = tid & 63;
    const int quad = lane >> 4, n16 = lane & 15;
    const int i0 = blockIdx.x * ITILE;

    for (int r = tid; r < ITILE; r += 512) { thr[r] = INFINITY; cnt[r] = 0; }

    // ---- A-fragments: persistent in registers. lane(q,n) holds
    //      A[m=n16][k=q*8..+8] of i-subtile is, k-chunk ks.
    short8 aF[4][4];
#pragma unroll
    for (int is = 0; is < 4; is++)
#pragma unroll
        for (int ks = 0; ks < 4; ks++)
            aF[is][ks] = *(const short8*)(Xhi + (size_t)(i0 + is * 16 + n16) * Dd + ks * 32 + quad * 8);

    __syncthreads();   // thr/cnt visible before first inserts

    // ---- B stream: this lane's fixed column j = j0 + wave*16 + n16
    const int jcol = wave * 16 + n16;
    const u16* bbase = Xhi + (size_t)jcol * Dd + quad * 8;
    short8 bc[4], bn[4];
    float sjc, sjn;
#pragma unroll
    for (int ks = 0; ks < 4; ks++) bn[ks] = *(const short8*)(bbase + ks * 32);
    sjn = sqn[jcol];

    for (int jt = 0; jt < NJT; jt++) {
        const int j0 = jt * JTILE;
#pragma unroll
        for (int ks = 0; ks < 4; ks++) bc[ks] = bn[ks];
        sjc = sjn;
        if (jt + 1 < NJT) {   // register double-buffer: prefetch next tile
            const u16* nb = bbase + (size_t)(jt + 1) * JTILE * Dd;
#pragma unroll
            for (int ks = 0; ks < 4; ks++) bn[ks] = *(const short8*)(nb + ks * 32);
            sjn = sqn[(jt + 1) * JTILE + jcol];
        }

        // ---- MFMA: 4 i-subtiles x 4 k-chunks, acc[is] = Xi_is . xj
        f32x4 acc[4];
#pragma unroll
        for (int is = 0; is < 4; is++) acc[is] = (f32x4){0.f, 0.f, 0.f, 0.f};
#pragma unroll
        for (int ks = 0; ks < 4; ks++)
#pragma unroll
            for (int is = 0; is < 4; is++)
                acc[is] = __builtin_amdgcn_mfma_f32_16x16x32_bf16(aF[is][ks], bc[ks], acc[is], 0, 0, 0);

        // ---- epilogue: approx key rv = sqn[j] - 2*dot; C-layout row = quad*4+r
        const int jj = j0 + jcol;
        unsigned pend = 0u;
#pragma unroll
        for (int is = 0; is < 4; is++)
#pragma unroll
            for (int r = 0; r < 4; r++) {
                const int il = is * 16 + quad * 4 + r;
                const float rv = fmaf(-2.f, acc[is][r], sjc);
                acc[is][r] = rv;
                if (rv < thr[il]) pend |= 1u << (is * 4 + r);
            }

        // ---- reservoir insert; barriers only via __syncthreads_or
        for (;;) {
            if (pend) {
#pragma unroll
                for (int is = 0; is < 4; is++)
#pragma unroll
                    for (int r = 0; r < 4; r++) {
                        const unsigned bit = 1u << (is * 4 + r);
                        if (pend & bit) {
                            const int il = is * 16 + quad * 4 + r;
                            const float rv = acc[is][r];
                            if (rv < thr[il]) {
                                const int pos = atomicAdd(&cnt[il], 1);
                                if (pos < LCAP) {
                                    listv[il][pos] = rv;
                                    listj[il][pos] = jj;
                                    pend &= ~bit;
                                }  // else retry after compaction
                            } else {
                                pend &= ~bit;
                            }
                        }
                    }
            }
            if (!__syncthreads_or(pend != 0u)) break;
            // compaction: wave owns rows [wave*8, wave*8+8)
#pragma unroll
            for (int rr8 = 0; rr8 < 8; rr8++) {
                const int rr = wave * 8 + rr8;
                if (cnt[rr] >= LCAP) {
                    const float v = (lane < LCAP) ? listv[rr][lane] : INFINITY;
                    const int j2 = (lane < LCAP) ? listj[rr][lane] : 0;
                    int rk = 0;
#pragma unroll 8
                    for (int s = 0; s < 64; s++) {
                        const float ov = __shfl(v, s);
                        rk += (ov < v || (ov == v && s < lane)) ? 1 : 0;
                    }
                    const unsigned long long m31 = __ballot(rk == Kk - 1);
                    const float v32 = __shfl(v, (int)(__ffsll(m31) - 1));
                    int m = __popcll(__ballot(v < v32 + BAND));
                    m = min(m, KEEP);
                    if (rk < m) { listv[rr][rk] = v; listj[rr][rk] = j2; }
                    if (lane == 0) { thr[rr] = v32 + BAND; cnt[rr] = m; }
                }
            }
            __syncthreads();
        }
    }

    // ================= exact fp32 re-rank of surviving candidates ==========
    __syncthreads();
    for (int t = tid; t < ITILE * Dd / 4; t += 512)
        ((float4*)xi32)[t] = ((const float4*)(X + (size_t)i0 * Dd))[t];
    __syncthreads();
#pragma unroll
    for (int rr8 = 0; rr8 < 8; rr8++) {
        const int rr = wave * 8 + rr8;
        const int n = min(cnt[rr], LCAP);
        const int jj = (lane < n) ? listj[rr][lane] : -1;
        float rv = INFINITY;
        if (jj >= 0) {
            const float* xj = X + (size_t)jj * Dd;
            float s0 = 0.f, s1 = 0.f, s2 = 0.f, s3 = 0.f;
#pragma unroll
            for (int d = 0; d < Dd; d += 4) {
                const float4 a = *(const float4*)(&xi32[rr][d]);
                const float4 b = *(const float4*)(xj + d);
                s0 = fmaf(a.x, b.x, s0); s1 = fmaf(a.y, b.y, s1);
                s2 = fmaf(a.z, b.z, s2); s3 = fmaf(a.w, b.w, s3);
            }
            rv = fmaf(-2.f, (s0 + s1) + (s2 + s3), sqn[jj]);
        }
        int rk = 0;
#pragma unroll 8
        for (int s = 0; s < 64; s++) {
            const float ov = __shfl(rv, s);
            rk += (ov < rv || (ov == rv && s < lane)) ? 1 : 0;
        }
        if (rk < Kk) idx_out[(size_t)(i0 + rr) * Kk + rk] = jj;
    }
}

// ------------------------------------------------- P = X@(W1a-W1b)+b1, Q = X@W1b
__global__ __launch_bounds__(256) void pq_kernel(const float* __restrict__ X,
                                                 const float* __restrict__ W1,
                                                 const float* __restrict__ b1,
                                                 float* __restrict__ P,
                                                 float* __restrict__ Q) {
    __shared__ float xrow[16][Dd];
    const int i0 = blockIdx.x * 16;
    for (int t = threadIdx.x; t < 16 * Dd / 4; t += 256)
        ((float4*)&xrow[0][0])[t] = ((const float4*)(X + (size_t)i0 * Dd))[t];
    __syncthreads();
    const int cc = threadIdx.x & 127;
    const int mat = threadIdx.x >> 7;
    float acc[16];
#pragma unroll
    for (int r = 0; r < 16; r++) acc[r] = 0.f;
    for (int d = 0; d < Dd; d++) {
        float w;
        if (mat == 0) w = W1[d * 128 + cc] - W1[(128 + d) * 128 + cc];
        else          w = W1[(128 + d) * 128 + cc];
#pragma unroll
        for (int r = 0; r < 16; r++) acc[r] = fmaf(xrow[r][d], w, acc[r]);
    }
    if (mat == 0) {
        const float b = b1[cc];
#pragma unroll
        for (int r = 0; r < 16; r++) P[(size_t)(i0 + r) * 128 + cc] = acc[r] + b;
    } else {
#pragma unroll
        for (int r = 0; r < 16; r++) Q[(size_t)(i0 + r) * 128 + cc] = acc[r];
    }
}

// ------------------------------------------- h1 = relu(P + max_k Q[idx]) ----
__global__ __launch_bounds__(128) void h1_kernel(const float* __restrict__ P,
                                                 const float* __restrict__ Q,
                                                 const int* __restrict__ idx,
                                                 float* __restrict__ h1) {
    const int i = blockIdx.x;
    const int c = threadIdx.x;
    __shared__ int jb[Kk];
    if (threadIdx.x < Kk) jb[threadIdx.x] = idx[(size_t)i * Kk + threadIdx.x];
    __syncthreads();
    float m = -INFINITY;
#pragma unroll
    for (int k = 0; k < Kk; k++) m = fmaxf(m, Q[(size_t)jb[k] * 128 + c]);
    h1[(size_t)i * 128 + c] = fmaxf(P[(size_t)i * 128 + c] + m, 0.f);
}

// --------------------------- P2 = h1@(W2a-W2b)+b2, Q2 = h1@W2b (C=10) -------
__global__ __launch_bounds__(256) void pq2_kernel(const float* __restrict__ h1,
                                                  const float* __restrict__ W2,
                                                  const float* __restrict__ b2,
                                                  float* __restrict__ P2,
                                                  float* __restrict__ Q2) {
    const int lane = threadIdx.x & 63;
    const int wave = threadIdx.x >> 6;
#pragma unroll
    for (int rr = 0; rr < 4; rr++) {
        const int i = blockIdx.x * 16 + wave * 4 + rr;
        const float2 h = *(const float2*)(h1 + (size_t)i * 128 + lane * 2);
#pragma unroll
        for (int c = 0; c < 10; c++) {
            const float wt0 = W2[(2 * lane) * 10 + c];
            const float wt1 = W2[(2 * lane + 1) * 10 + c];
            const float wb0 = W2[(128 + 2 * lane) * 10 + c];
            const float wb1 = W2[(129 + 2 * lane) * 10 + c];
            float pa = fmaf(h.x, wt0, h.y * wt1);
            float pb = fmaf(h.x, wb0, h.y * wb1);
#pragma unroll
            for (int o = 32; o > 0; o >>= 1) {
                pa += __shfl_down(pa, o);
                pb += __shfl_down(pb, o);
            }
            if (lane == 0) {
                P2[(size_t)i * 10 + c] = pa - pb + b2[c];
                Q2[(size_t)i * 10 + c] = pb;
            }
        }
    }
}

// ---------------------------------- out = P2 + max_k Q2[idx] (no relu) ------
__global__ __launch_bounds__(256) void out_kernel(const float* __restrict__ P2,
                                                  const float* __restrict__ Q2,
                                                  const int* __restrict__ idx,
                                                  float* __restrict__ out) {
    const int g = blockIdx.x * 256 + threadIdx.x;
    const int i = g >> 4;
    const int c = g & 15;
    if (c >= 10) return;
    const int* jr = idx + (size_t)i * Kk;
    float m = -INFINITY;
#pragma unroll
    for (int k = 0; k < Kk; k++) m = fmaxf(m, Q2[(size_t)jr[k] * 10 + c]);
    out[(size_t)i * 10 + c] = P2[(size_t)i * 10 + c] + m;
}

extern "C" void kernel_launch(void* const* d_in, const int* in_sizes, int n_in,
                              void* d_out, int out_size, void* d_ws, size_t ws_size,
                              hipStream_t stream) {
    const float* X  = (const float*)d_in[0];
    const float* W1 = (const float*)d_in[1];
    const float* b1 = (const float*)d_in[2];
    const float* W2 = (const float*)d_in[3];
    const float* b2 = (const float*)d_in[4];
    float* out = (float*)d_out;

    char* ws = (char*)d_ws;
    float* sqn = (float*)ws;                                  // 64 KB
    int*   idx = (int*)(ws + (1 << 16));                      // 2 MB
    u16*   Xhi = (u16*)(ws + 2162688);                        // 4 MB
    float* P   = (float*)(ws + 6356992);                      // 8 MB
    float* Q   = P + (size_t)Nn * 128;                        // 8 MB
    float* h1  = Q + (size_t)Nn * 128;                        // 8 MB
    float* P2  = h1 + (size_t)Nn * 128;                       // 640 KB
    float* Q2  = P2 + (size_t)Nn * 10;                        // 640 KB

    cvt_kernel<<<Nn * Dd / 4 / 256, 256, 0, stream>>>(X, Xhi);
    sqn_kernel<<<Nn / 4, 256, 0, stream>>>(X, sqn);
    knn_kernel<<<Nn / ITILE, 512, 0, stream>>>(X, Xhi, sqn, idx);
    pq_kernel<<<Nn / 16, 256, 0, stream>>>(X, W1, b1, P, Q);
    h1_kernel<<<Nn, 128, 0, stream>>>(P, Q, idx, h1);
    pq2_kernel<<<Nn / 16, 256, 0, stream>>>(h1, W2, b2, P2, Q2);
    out_kernel<<<Nn * 16 / 256, 256, 0, stream>>>(P2, Q2, idx, out);
}

// Round 6
// 886.083 us; speedup vs baseline: 2.4568x; 1.3968x over previous
//
#include <hip/hip_runtime.h>
#include <math.h>

#define Nn 16384
#define Dd 128
#define Kk 32
#define JSPLIT 4
#define JCH (Nn / JSPLIT)     // 4096 j per chunk
#define NG (JCH / 16)         // 256 groups of 16 j
#define LCAP2 96              // reservoir slots per row
#define CTRIG 80              // compact when cnt >= CTRIG (burst <= 16 -> max 95)
#define CKEEP 63              // keep cap after streaming compaction
#define FKEEP 48              // candidates written per (row, chunk)
#define BAND 0.5f             // ~10 sigma of hi-bf16 d2 error

typedef unsigned short u16;
typedef short short8 __attribute__((ext_vector_type(8)));
typedef float f32x4 __attribute__((ext_vector_type(4)));
struct __attribute__((aligned(8))) u16x4 { u16 x, y, z, w; };

__device__ __forceinline__ u16 f2bf(float x) {
    unsigned u = __float_as_uint(x);
    unsigned r = u + 0x7FFFu + ((u >> 16) & 1u);   // RN-even
    return (u16)(r >> 16);
}

// ------------------------------------------------------- bf16 convert ------
__global__ __launch_bounds__(256) void cvt_kernel(const float* __restrict__ X,
                                                  u16* __restrict__ hi) {
    const int g = blockIdx.x * 256 + threadIdx.x;
    const float4 v = ((const float4*)X)[g];
    u16x4 h;
    h.x = f2bf(v.x); h.y = f2bf(v.y); h.z = f2bf(v.z); h.w = f2bf(v.w);
    ((u16x4*)hi)[g] = h;
}

// ---------------------------------------------------------------- sqn ------
__global__ __launch_bounds__(256) void sqn_kernel(const float* __restrict__ X,
                                                  float* __restrict__ sqn) {
    const int i = blockIdx.x * 4 + (threadIdx.x >> 6);
    const int lane = threadIdx.x & 63;
    float2 v = *(const float2*)(X + (size_t)i * Dd + lane * 2);
    float s = fmaf(v.x, v.x, v.y * v.y);
#pragma unroll
    for (int o = 32; o > 0; o >>= 1) s += __shfl_down(s, o);
    if (lane == 0) sqn[i] = s;
}

// -------- wave-wide compact/select of one reservoir row (<=95 entries) -----
// Bisect for hi with count(<hi) in [32,48]; keep all < cut where cut starts at
// hi+BAND and, if over capacity, is REFINED BY VALUE (drop largest first) --
// round-5's slot-order truncation was the correctness bug.
__device__ __forceinline__ void compact_row(
    int row, int lane, bool final_pass,
    float (*listv)[LCAP2], u16 (*listj)[LCAP2], float* thrS, int* cnt,
    u16* candOut, int* candCntOut) {
    const int n = cnt[row];
    float v0 = INFINITY, v1 = INFINITY;
    u16 j0 = 0, j1 = 0;
    if (lane < n)      { v0 = listv[row][lane];      j0 = listj[row][lane]; }
    if (lane + 64 < n) { v1 = listv[row][lane + 64]; j1 = listj[row][lane + 64]; }
    float mn = fminf(v0, v1);
    float mx = fmaxf(v0 < INFINITY ? v0 : -INFINITY, v1 < INFINITY ? v1 : -INFINITY);
#pragma unroll
    for (int o = 32; o; o >>= 1) {
        mn = fminf(mn, __shfl_xor(mn, o));
        mx = fmaxf(mx, __shfl_xor(mx, o));
    }
    float lo = mn, hi = mx + 1.0f;
    for (int it = 0; it < 12; it++) {
        const float mid = 0.5f * (lo + hi);
        const int c = __popcll(__ballot(v0 < mid)) + __popcll(__ballot(v1 < mid));
        if (c >= Kk) { hi = mid; if (c <= 48) break; }
        else lo = mid;
    }
    const int cap = final_pass ? FKEEP : CKEEP;
    float cut = hi + BAND;
    int m = __popcll(__ballot(v0 < cut)) + __popcll(__ballot(v1 < cut));
    if (m > cap) {
        // value-ordered cap: largest cut in [hi, hi+BAND] with count <= cap.
        // Invariant: count(<hi) <= 48 <= cap (bisection break condition).
        float cl = hi, ch = cut;
        for (int it = 0; it < 10; it++) {
            const float mid = 0.5f * (cl + ch);
            const int c = __popcll(__ballot(v0 < mid)) + __popcll(__ballot(v1 < mid));
            if (c <= cap) cl = mid; else ch = mid;
        }
        cut = cl;
        m = __popcll(__ballot(v0 < cut)) + __popcll(__ballot(v1 < cut));
        m = min(m, cap);   // tie-cluster failsafe (count(<hi)>48 pathological)
    }
    const unsigned long long m0 = __ballot(v0 < cut);
    const unsigned long long m1 = __ballot(v1 < cut);
    const int c0 = __popcll(m0);
    const unsigned long long ltm = (1ull << lane) - 1ull;
    const int p0 = __popcll(m0 & ltm);
    const int p1 = c0 + __popcll(m1 & ltm);
    const bool k0 = ((m0 >> lane) & 1) && (p0 < cap);
    const bool k1 = ((m1 >> lane) & 1) && (p1 < cap);
    if (final_pass) {
        if (k0) candOut[p0] = j0;
        if (k1) candOut[p1] = j1;
        if (lane == 0) *candCntOut = m;
    } else {
        if (k0) { listv[row][p0] = v0; listj[row][p0] = j0; }
        if (k1) { listv[row][p1] = v1; listj[row][p1] = j1; }
        if (lane == 0) { cnt[row] = m; thrS[row] = cut; }
    }
}

// ----------------------------------------------------------- knn filter ----
// 1024 blocks (256 i-tiles x 4 j-chunks) x 256 threads (4 waves, 4 blocks/CU).
// Wave owns 16 i-rows: A-frag = 16 VGPRs, resident. B = 4 direct dwordx4
// global loads per 16-j group, register double-buffered. Wave-private
// reservoir, thresholds in registers, ZERO barriers in the hot loop.
__global__ __launch_bounds__(256, 4) void knn_filter(const u16* __restrict__ Xhi,
                                                     const float* __restrict__ sqn,
                                                     u16* __restrict__ cand,
                                                     int* __restrict__ candCnt) {
    __shared__ float listv[64][LCAP2];   // 24 KB
    __shared__ u16   listj[64][LCAP2];   // 12 KB
    __shared__ float thrS[64];
    __shared__ int   cnt[64];

    const int tid = threadIdx.x;
    const int wave = tid >> 6, lane = tid & 63;
    const int quad = lane >> 4, n16 = lane & 15;
    const int itile = blockIdx.x >> 2, chunk = blockIdx.x & 3;
    const int ibase = itile * 64;
    const int jch0 = chunk * JCH;

    if (tid < 64) { thrS[tid] = INFINITY; cnt[tid] = 0; }
    __syncthreads();   // one-time

    short8 aF[4];
    {
        const u16* arow = Xhi + (size_t)(ibase + wave * 16 + n16) * Dd + quad * 8;
#pragma unroll
        for (int ks = 0; ks < 4; ks++) aF[ks] = *(const short8*)(arow + ks * 32);
    }
    float thrReg[4] = {INFINITY, INFINITY, INFINITY, INFINITY};

    const u16* bbase = Xhi + (size_t)(jch0 + n16) * Dd + quad * 8;
    short8 bc[4], bn[4];
    float sjc, sjn;
#pragma unroll
    for (int ks = 0; ks < 4; ks++) bn[ks] = *(const short8*)(bbase + ks * 32);
    sjn = sqn[jch0 + n16];

    for (int g = 0; g < NG; g++) {
#pragma unroll
        for (int ks = 0; ks < 4; ks++) bc[ks] = bn[ks];
        sjc = sjn;
        if (g + 1 < NG) {
            const u16* nb = bbase + (size_t)(g + 1) * 16 * Dd;
#pragma unroll
            for (int ks = 0; ks < 4; ks++) bn[ks] = *(const short8*)(nb + ks * 32);
            sjn = sqn[jch0 + (g + 1) * 16 + n16];
        }
        f32x4 a01 = {0.f, 0.f, 0.f, 0.f}, a23 = {0.f, 0.f, 0.f, 0.f};
        a01 = __builtin_amdgcn_mfma_f32_16x16x32_bf16(aF[0], bc[0], a01, 0, 0, 0);
        a23 = __builtin_amdgcn_mfma_f32_16x16x32_bf16(aF[2], bc[2], a23, 0, 0, 0);
        a01 = __builtin_amdgcn_mfma_f32_16x16x32_bf16(aF[1], bc[1], a01, 0, 0, 0);
        a23 = __builtin_amdgcn_mfma_f32_16x16x32_bf16(aF[3], bc[3], a23, 0, 0, 0);

        const int jj = jch0 + g * 16 + n16;
        float rv[4];
        int pend = 0;
#pragma unroll
        for (int r = 0; r < 4; r++) {
            rv[r] = fmaf(-2.f, a01[r] + a23[r], sjc);
            if (rv[r] < thrReg[r]) pend |= 1 << r;
        }
        if (__any(pend)) {
#pragma unroll
            for (int r = 0; r < 4; r++)
                if (pend & (1 << r)) {
                    const int row = wave * 16 + quad * 4 + r;
                    const int pos = atomicAdd(&cnt[row], 1);  // always < LCAP2
                    listv[row][pos] = rv[r];
                    listj[row][pos] = (u16)jj;
                }
            const int myrow = wave * 16 + n16;
            unsigned long long ovm = __ballot(cnt[myrow] >= CTRIG) & 0xFFFFull;
            if (ovm) {
                while (ovm) {
                    const int rl = (int)(__ffsll(ovm) - 1);
                    ovm &= ovm - 1;
                    compact_row(wave * 16 + rl, lane, false, listv, listj, thrS, cnt, 0, 0);
                }
#pragma unroll
                for (int r = 0; r < 4; r++) thrReg[r] = thrS[wave * 16 + quad * 4 + r];
            }
        }
    }

    // final: per-row select (<=FKEEP within band) -> global candidate lists
    for (int rl = 0; rl < 16; rl++) {
        const int row = wave * 16 + rl;
        const int gi = ibase + row;
        u16* co = cand + ((size_t)gi * JSPLIT + chunk) * FKEEP;
        int* cc = candCnt + (size_t)gi * JSPLIT + chunk;
        compact_row(row, lane, true, listv, listj, thrS, cnt, co, cc);
    }
}

// ----------------------------------------------------------- knn exact -----
// 4096 blocks x 256 (wave = one row). Exact fp32 re-rank of the union of the
// 4 per-chunk candidate lists (<=192 slots, 3 per lane).
__global__ __launch_bounds__(256) void knn_exact(const float* __restrict__ X,
                                                 const float* __restrict__ sqn,
                                                 const u16* __restrict__ cand,
                                                 const int* __restrict__ candCnt,
                                                 int* __restrict__ idx_out) {
    __shared__ float xiS[4][Dd];
    const int wave = threadIdx.x >> 6, lane = threadIdx.x & 63;
    const int i = blockIdx.x * 4 + wave;
    *(float2*)&xiS[wave][lane * 2] = *(const float2*)(X + (size_t)i * Dd + lane * 2);
    int cnts[JSPLIT];
#pragma unroll
    for (int k = 0; k < JSPLIT; k++) cnts[k] = candCnt[(size_t)i * JSPLIT + k];
    float rv[3];
    int jd[3];
#pragma unroll
    for (int s = 0; s < 3; s++) {
        const int slot = lane + 64 * s;
        const int k = slot / FKEEP, t = slot - k * FKEEP;
        rv[s] = INFINITY; jd[s] = -1;
        if (t < cnts[k]) {
            const int jj = cand[((size_t)i * JSPLIT + k) * FKEEP + t];
            const float* xj = X + (size_t)jj * Dd;
            float s0 = 0.f, s1 = 0.f, s2 = 0.f, s3 = 0.f;
#pragma unroll
            for (int d = 0; d < Dd; d += 4) {
                const float4 a = *(const float4*)&xiS[wave][d];
                const float4 b = *(const float4*)(xj + d);
                s0 = fmaf(a.x, b.x, s0); s1 = fmaf(a.y, b.y, s1);
                s2 = fmaf(a.z, b.z, s2); s3 = fmaf(a.w, b.w, s3);
            }
            rv[s] = fmaf(-2.f, (s0 + s1) + (s2 + s3), sqn[jj]);
            jd[s] = jj;
        }
    }
    int rk[3] = {0, 0, 0};
    for (int s2 = 0; s2 < 64; s2++) {
        const float o0 = __shfl(rv[0], s2);
        const float o1 = __shfl(rv[1], s2);
        const float o2 = __shfl(rv[2], s2);
#pragma unroll
        for (int s = 0; s < 3; s++) {
            const int myid = lane + 64 * s;
            rk[s] += (o0 < rv[s] || (o0 == rv[s] && s2 < myid)) ? 1 : 0;
            rk[s] += (o1 < rv[s] || (o1 == rv[s] && s2 + 64 < myid)) ? 1 : 0;
            rk[s] += (o2 < rv[s] || (o2 == rv[s] && s2 + 128 < myid)) ? 1 : 0;
        }
    }
#pragma unroll
    for (int s = 0; s < 3; s++)
        if (jd[s] >= 0 && rk[s] < Kk) idx_out[(size_t)i * Kk + rk[s]] = jd[s];
}

// ------------------------------------------------- P = X@(W1a-W1b)+b1, Q = X@W1b
__global__ __launch_bounds__(256) void pq_kernel(const float* __restrict__ X,
                                                 const float* __restrict__ W1,
                                                 const float* __restrict__ b1,
                                                 float* __restrict__ P,
                                                 float* __restrict__ Q) {
    __shared__ float xrow[16][Dd];
    const int i0 = blockIdx.x * 16;
    for (int t = threadIdx.x; t < 16 * Dd / 4; t += 256)
        ((float4*)&xrow[0][0])[t] = ((const float4*)(X + (size_t)i0 * Dd))[t];
    __syncthreads();
    const int cc = threadIdx.x & 127;
    const int mat = threadIdx.x >> 7;
    float acc[16];
#pragma unroll
    for (int r = 0; r < 16; r++) acc[r] = 0.f;
    for (int d = 0; d < Dd; d++) {
        float w;
        if (mat == 0) w = W1[d * 128 + cc] - W1[(128 + d) * 128 + cc];
        else          w = W1[(128 + d) * 128 + cc];
#pragma unroll
        for (int r = 0; r < 16; r++) acc[r] = fmaf(xrow[r][d], w, acc[r]);
    }
    if (mat == 0) {
        const float b = b1[cc];
#pragma unroll
        for (int r = 0; r < 16; r++) P[(size_t)(i0 + r) * 128 + cc] = acc[r] + b;
    } else {
#pragma unroll
        for (int r = 0; r < 16; r++) Q[(size_t)(i0 + r) * 128 + cc] = acc[r];
    }
}

// ------------------------------------------- h1 = relu(P + max_k Q[idx]) ----
__global__ __launch_bounds__(128) void h1_kernel(const float* __restrict__ P,
                                                 const float* __restrict__ Q,
                                                 const int* __restrict__ idx,
                                                 float* __restrict__ h1) {
    const int i = blockIdx.x;
    const int c = threadIdx.x;
    __shared__ int jb[Kk];
    if (threadIdx.x < Kk) jb[threadIdx.x] = idx[(size_t)i * Kk + threadIdx.x];
    __syncthreads();
    float m = -INFINITY;
#pragma unroll
    for (int k = 0; k < Kk; k++) m = fmaxf(m, Q[(size_t)jb[k] * 128 + c]);
    h1[(size_t)i * 128 + c] = fmaxf(P[(size_t)i * 128 + c] + m, 0.f);
}

// --------------------------- P2 = h1@(W2a-W2b)+b2, Q2 = h1@W2b (C=10) -------
__global__ __launch_bounds__(256) void pq2_kernel(const float* __restrict__ h1,
                                                  const float* __restrict__ W2,
                                                  const float* __restrict__ b2,
                                                  float* __restrict__ P2,
                                                  float* __restrict__ Q2) {
    const int lane = threadIdx.x & 63;
    const int wave = threadIdx.x >> 6;
#pragma unroll
    for (int rr = 0; rr < 4; rr++) {
        const int i = blockIdx.x * 16 + wave * 4 + rr;
        const float2 h = *(const float2*)(h1 + (size_t)i * 128 + lane * 2);
#pragma unroll
        for (int c = 0; c < 10; c++) {
            const float wt0 = W2[(2 * lane) * 10 + c];
            const float wt1 = W2[(2 * lane + 1) * 10 + c];
            const float wb0 = W2[(128 + 2 * lane) * 10 + c];
            const float wb1 = W2[(129 + 2 * lane) * 10 + c];
            float pa = fmaf(h.x, wt0, h.y * wt1);
            float pb = fmaf(h.x, wb0, h.y * wb1);
#pragma unroll
            for (int o = 32; o > 0; o >>= 1) {
                pa += __shfl_down(pa, o);
                pb += __shfl_down(pb, o);
            }
            if (lane == 0) {
                P2[(size_t)i * 10 + c] = pa - pb + b2[c];
                Q2[(size_t)i * 10 + c] = pb;
            }
        }
    }
}

// ---------------------------------- out = P2 + max_k Q2[idx] (no relu) ------
__global__ __launch_bounds__(256) void out_kernel(const float* __restrict__ P2,
                                                  const float* __restrict__ Q2,
                                                  const int* __restrict__ idx,
                                                  float* __restrict__ out) {
    const int g = blockIdx.x * 256 + threadIdx.x;
    const int i = g >> 4;
    const int c = g & 15;
    if (c >= 10) return;
    const int* jr = idx + (size_t)i * Kk;
    float m = -INFINITY;
#pragma unroll
    for (int k = 0; k < Kk; k++) m = fmaxf(m, Q2[(size_t)jr[k] * 10 + c]);
    out[(size_t)i * 10 + c] = P2[(size_t)i * 10 + c] + m;
}

extern "C" void kernel_launch(void* const* d_in, const int* in_sizes, int n_in,
                              void* d_out, int out_size, void* d_ws, size_t ws_size,
                              hipStream_t stream) {
    const float* X  = (const float*)d_in[0];
    const float* W1 = (const float*)d_in[1];
    const float* b1 = (const float*)d_in[2];
    const float* W2 = (const float*)d_in[3];
    const float* b2 = (const float*)d_in[4];
    float* out = (float*)d_out;

    char* ws = (char*)d_ws;
    float* sqn = (float*)ws;                                  // 64 KB
    int*   idx = (int*)(ws + (1 << 16));                      // 2 MB
    u16*   Xhi = (u16*)(ws + 2162688);                        // 4 MB
    float* P   = (float*)(ws + 6356992);                      // 8 MB
    float* Q   = P + (size_t)Nn * 128;                        // 8 MB
    float* h1  = Q + (size_t)Nn * 128;                        // 8 MB
    float* P2  = h1 + (size_t)Nn * 128;                       // 640 KB
    float* Q2  = P2 + (size_t)Nn * 10;                        // 640 KB
    // candidate lists alias the P region (consumed by knn_exact BEFORE
    // pq_kernel writes P — same-stream kernels serialize):
    u16* cand    = (u16*)P;                                   // 6 MB
    int* candCnt = (int*)((char*)P + 6 * 1024 * 1024 + 512 * 1024);  // 256 KB

    cvt_kernel<<<Nn * Dd / 4 / 256, 256, 0, stream>>>(X, Xhi);
    sqn_kernel<<<Nn / 4, 256, 0, stream>>>(X, sqn);
    knn_filter<<<256 * JSPLIT, 256, 0, stream>>>(Xhi, sqn, cand, candCnt);
    knn_exact<<<Nn / 4, 256, 0, stream>>>(X, sqn, cand, candCnt, idx);
    pq_kernel<<<Nn / 16, 256, 0, stream>>>(X, W1, b1, P, Q);
    h1_kernel<<<Nn, 128, 0, stream>>>(P, Q, idx, h1);
    pq2_kernel<<<Nn / 16, 256, 0, stream>>>(h1, W2, b2, P2, Q2);
    out_kernel<<<Nn * 16 / 256, 256, 0, stream>>>(P2, Q2, idx, out);
}

// Round 7
// 878.578 us; speedup vs baseline: 2.4778x; 1.0085x over previous
//
#include <hip/hip_runtime.h>
#include <math.h>

#define Nn 16384
#define Dd 128
#define Kk 32
#define JSPLIT 4
#define JCH (Nn / JSPLIT)     // 4096 j per chunk
#define NG (JCH / 16)         // 256 groups of 16 j
#define LCAP2 96              // reservoir slots per row
#define CTRIG 80              // compact when cnt >= CTRIG (burst <= 16 -> max 95)
#define CKEEP 63              // keep cap after streaming compaction
#define FKEEP 48              // candidates written per (row, chunk)
#define BAND 0.4f             // ~7 sigma of hi-bf16 d2 error (0.5 validated r4/r6)

typedef unsigned short u16;
typedef short short8 __attribute__((ext_vector_type(8)));
typedef float f32x4 __attribute__((ext_vector_type(4)));
struct __attribute__((aligned(8))) u16x4 { u16 x, y, z, w; };

__device__ __forceinline__ u16 f2bf(float x) {
    unsigned u = __float_as_uint(x);
    unsigned r = u + 0x7FFFu + ((u >> 16) & 1u);   // RN-even
    return (u16)(r >> 16);
}

// ------------------------------------------------------- bf16 convert ------
__global__ __launch_bounds__(256) void cvt_kernel(const float* __restrict__ X,
                                                  u16* __restrict__ hi) {
    const int g = blockIdx.x * 256 + threadIdx.x;
    const float4 v = ((const float4*)X)[g];
    u16x4 h;
    h.x = f2bf(v.x); h.y = f2bf(v.y); h.z = f2bf(v.z); h.w = f2bf(v.w);
    ((u16x4*)hi)[g] = h;
}

// ---------------------------------------------------------------- sqn ------
__global__ __launch_bounds__(256) void sqn_kernel(const float* __restrict__ X,
                                                  float* __restrict__ sqn) {
    const int i = blockIdx.x * 4 + (threadIdx.x >> 6);
    const int lane = threadIdx.x & 63;
    float2 v = *(const float2*)(X + (size_t)i * Dd + lane * 2);
    float s = fmaf(v.x, v.x, v.y * v.y);
#pragma unroll
    for (int o = 32; o > 0; o >>= 1) s += __shfl_down(s, o);
    if (lane == 0) sqn[i] = s;
}

// -------- wave-wide compact/select of one reservoir row (<=95 entries) -----
// Bisect for hi with count(<hi) in [32,48]; keep all < cut = hi+BAND; if over
// capacity, refine cut BY VALUE (drop largest first) -- round-6-validated.
__device__ __forceinline__ void compact_row(
    int row, int lane, bool final_pass,
    float (*listv)[LCAP2], u16 (*listj)[LCAP2], float* thrS, int* cnt,
    u16* candOut, int* candCntOut) {
    const int n = cnt[row];
    float v0 = INFINITY, v1 = INFINITY;
    u16 j0 = 0, j1 = 0;
    if (lane < n)      { v0 = listv[row][lane];      j0 = listj[row][lane]; }
    if (lane + 64 < n) { v1 = listv[row][lane + 64]; j1 = listj[row][lane + 64]; }
    float mn = fminf(v0, v1);
    float mx = fmaxf(v0 < INFINITY ? v0 : -INFINITY, v1 < INFINITY ? v1 : -INFINITY);
#pragma unroll
    for (int o = 32; o; o >>= 1) {
        mn = fminf(mn, __shfl_xor(mn, o));
        mx = fmaxf(mx, __shfl_xor(mx, o));
    }
    float lo = mn, hi = mx + 1.0f;
    for (int it = 0; it < 12; it++) {
        const float mid = 0.5f * (lo + hi);
        const int c = __popcll(__ballot(v0 < mid)) + __popcll(__ballot(v1 < mid));
        if (c >= Kk) { hi = mid; if (c <= 48) break; }
        else lo = mid;
    }
    const int cap = final_pass ? FKEEP : CKEEP;
    float cut = hi + BAND;
    int m = __popcll(__ballot(v0 < cut)) + __popcll(__ballot(v1 < cut));
    if (m > cap) {
        // value-ordered cap: largest cut in [hi, hi+BAND] with count <= cap.
        float cl = hi, ch = cut;
        for (int it = 0; it < 10; it++) {
            const float mid = 0.5f * (cl + ch);
            const int c = __popcll(__ballot(v0 < mid)) + __popcll(__ballot(v1 < mid));
            if (c <= cap) cl = mid; else ch = mid;
        }
        cut = cl;
        m = __popcll(__ballot(v0 < cut)) + __popcll(__ballot(v1 < cut));
        m = min(m, cap);   // tie-cluster failsafe
    }
    const unsigned long long m0 = __ballot(v0 < cut);
    const unsigned long long m1 = __ballot(v1 < cut);
    const int c0 = __popcll(m0);
    const unsigned long long ltm = (1ull << lane) - 1ull;
    const int p0 = __popcll(m0 & ltm);
    const int p1 = c0 + __popcll(m1 & ltm);
    const bool k0 = ((m0 >> lane) & 1) && (p0 < cap);
    const bool k1 = ((m1 >> lane) & 1) && (p1 < cap);
    if (final_pass) {
        if (k0) candOut[p0] = j0;
        if (k1) candOut[p1] = j1;
        if (lane == 0) *candCntOut = m;
    } else {
        if (k0) { listv[row][p0] = v0; listj[row][p0] = j0; }
        if (k1) { listv[row][p1] = v1; listj[row][p1] = j1; }
        if (lane == 0) { cnt[row] = m; thrS[row] = cut; }
    }
}

// ----------------------------------------------------------- knn filter ----
// 1024 blocks (256 i-tiles x 4 j-chunks) x 256 threads (4 waves, 4 blocks/CU).
// Wave owns 16 i-rows (A-frag resident, 16 VGPRs). B streamed via direct
// dwordx4 loads, register TRIPLE-buffered (prefetch distance 2). Inserts use
// aggregated ballot ranks + ONE single-lane LDS atomic per (row,group);
// overflow trigger comes from the atomic return -- no extra LDS read, no
// same-address atomic serialization. Zero barriers in the hot loop.
__global__ __launch_bounds__(256, 4) void knn_filter(const u16* __restrict__ Xhi,
                                                     const float* __restrict__ sqn,
                                                     u16* __restrict__ cand,
                                                     int* __restrict__ candCnt) {
    __shared__ float listv[64][LCAP2];   // 24 KB
    __shared__ u16   listj[64][LCAP2];   // 12 KB
    __shared__ float thrS[64];
    __shared__ int   cnt[64];

    const int tid = threadIdx.x;
    const int wave = tid >> 6, lane = tid & 63;
    const int quad = lane >> 4, n16 = lane & 15;
    const int wave16 = wave * 16;
    const int itile = blockIdx.x >> 2, chunk = blockIdx.x & 3;
    const int ibase = itile * 64;
    const int jch0 = chunk * JCH;

    if (tid < 64) { thrS[tid] = INFINITY; cnt[tid] = 0; }
    __syncthreads();   // one-time

    short8 aF[4];
    {
        const u16* arow = Xhi + (size_t)(ibase + wave16 + n16) * Dd + quad * 8;
#pragma unroll
        for (int ks = 0; ks < 4; ks++) aF[ks] = *(const short8*)(arow + ks * 32);
    }
    float thrReg[4] = {INFINITY, INFINITY, INFINITY, INFINITY};

    const u16* bbase = Xhi + (size_t)(jch0 + n16) * Dd + quad * 8;
    short8 bc[4], b1v[4], b2v[4];
    float sjc, sj1, sj2;
#pragma unroll
    for (int ks = 0; ks < 4; ks++) b1v[ks] = *(const short8*)(bbase + ks * 32);
    sj1 = sqn[jch0 + n16];
#pragma unroll
    for (int ks = 0; ks < 4; ks++) b2v[ks] = *(const short8*)(bbase + 16 * Dd + ks * 32);
    sj2 = sqn[jch0 + 16 + n16];

    for (int g = 0; g < NG; g++) {
#pragma unroll
        for (int ks = 0; ks < 4; ks++) bc[ks] = b1v[ks];
        sjc = sj1;
#pragma unroll
        for (int ks = 0; ks < 4; ks++) b1v[ks] = b2v[ks];
        sj1 = sj2;
        if (g + 2 < NG) {   // prefetch distance 2
            const u16* nb = bbase + (size_t)(g + 2) * 16 * Dd;
#pragma unroll
            for (int ks = 0; ks < 4; ks++) b2v[ks] = *(const short8*)(nb + ks * 32);
            sj2 = sqn[jch0 + (g + 2) * 16 + n16];
        }
        f32x4 a01 = {0.f, 0.f, 0.f, 0.f}, a23 = {0.f, 0.f, 0.f, 0.f};
        a01 = __builtin_amdgcn_mfma_f32_16x16x32_bf16(aF[0], bc[0], a01, 0, 0, 0);
        a23 = __builtin_amdgcn_mfma_f32_16x16x32_bf16(aF[2], bc[2], a23, 0, 0, 0);
        a01 = __builtin_amdgcn_mfma_f32_16x16x32_bf16(aF[1], bc[1], a01, 0, 0, 0);
        a23 = __builtin_amdgcn_mfma_f32_16x16x32_bf16(aF[3], bc[3], a23, 0, 0, 0);

        const int jj = jch0 + g * 16 + n16;
        float rv[4];
        int pend = 0;
#pragma unroll
        for (int r = 0; r < 4; r++) {
            rv[r] = fmaf(-2.f, a01[r] + a23[r], sjc);
            if (rv[r] < thrReg[r]) pend |= 1 << r;
        }
        if (__any(pend)) {
            bool trig = false;
#pragma unroll
            for (int r = 0; r < 4; r++) {
                const unsigned long long mr = __ballot((pend >> r) & 1);
                const unsigned qm = (unsigned)((mr >> (quad * 16)) & 0xFFFFull);
                if (qm) {   // quad-uniform branch
                    const int row = wave16 + quad * 4 + r;
                    const int qcnt = __popc(qm);
                    const int leader = (quad << 4) + (__ffs(qm) - 1);
                    int base = 0;
                    if (lane == leader) base = atomicAdd(&cnt[row], qcnt);
                    base = __shfl(base, leader);
                    if ((qm >> n16) & 1) {
                        const int pos = base + __popc(qm & ((1u << n16) - 1));
                        listv[row][pos] = rv[r];
                        listj[row][pos] = (u16)jj;
                    }
                    if (base + qcnt >= CTRIG) trig = true;
                }
            }
            if (__any(trig)) {   // rare path
                unsigned long long ovm =
                    __ballot(cnt[wave16 + n16] >= CTRIG) & 0xFFFFull;
                while (ovm) {
                    const int rl = (int)(__ffsll(ovm) - 1);
                    ovm &= ovm - 1;
                    compact_row(wave16 + rl, lane, false, listv, listj, thrS, cnt, 0, 0);
                }
#pragma unroll
                for (int r = 0; r < 4; r++) thrReg[r] = thrS[wave16 + quad * 4 + r];
            }
        }
    }

    // final: per-row select (<=FKEEP within band) -> global candidate lists
    for (int rl = 0; rl < 16; rl++) {
        const int row = wave16 + rl;
        const int gi = ibase + row;
        u16* co = cand + ((size_t)gi * JSPLIT + chunk) * FKEEP;
        int* cc = candCnt + (size_t)gi * JSPLIT + chunk;
        compact_row(row, lane, true, listv, listj, thrS, cnt, co, cc);
    }
}

// ----------------------------------------------------------- knn exact -----
// 4096 blocks x 256 (wave = one row). Exact fp32 re-rank of the union of the
// 4 per-chunk candidate lists (<=192 slots, 3 per lane).
__global__ __launch_bounds__(256) void knn_exact(const float* __restrict__ X,
                                                 const float* __restrict__ sqn,
                                                 const u16* __restrict__ cand,
                                                 const int* __restrict__ candCnt,
                                                 int* __restrict__ idx_out) {
    __shared__ float xiS[4][Dd];
    const int wave = threadIdx.x >> 6, lane = threadIdx.x & 63;
    const int i = blockIdx.x * 4 + wave;
    *(float2*)&xiS[wave][lane * 2] = *(const float2*)(X + (size_t)i * Dd + lane * 2);
    int cnts[JSPLIT];
#pragma unroll
    for (int k = 0; k < JSPLIT; k++) cnts[k] = candCnt[(size_t)i * JSPLIT + k];
    float rv[3];
    int jd[3];
#pragma unroll
    for (int s = 0; s < 3; s++) {
        const int slot = lane + 64 * s;
        const int k = slot / FKEEP, t = slot - k * FKEEP;
        rv[s] = INFINITY; jd[s] = -1;
        if (t < cnts[k]) {
            const int jj = cand[((size_t)i * JSPLIT + k) * FKEEP + t];
            const float* xj = X + (size_t)jj * Dd;
            float s0 = 0.f, s1 = 0.f, s2 = 0.f, s3 = 0.f;
#pragma unroll
            for (int d = 0; d < Dd; d += 4) {
                const float4 a = *(const float4*)&xiS[wave][d];
                const float4 b = *(const float4*)(xj + d);
                s0 = fmaf(a.x, b.x, s0); s1 = fmaf(a.y, b.y, s1);
                s2 = fmaf(a.z, b.z, s2); s3 = fmaf(a.w, b.w, s3);
            }
            rv[s] = fmaf(-2.f, (s0 + s1) + (s2 + s3), sqn[jj]);
            jd[s] = jj;
        }
    }
    int rk[3] = {0, 0, 0};
    for (int s2 = 0; s2 < 64; s2++) {
        const float o0 = __shfl(rv[0], s2);
        const float o1 = __shfl(rv[1], s2);
        const float o2 = __shfl(rv[2], s2);
#pragma unroll
        for (int s = 0; s < 3; s++) {
            const int myid = lane + 64 * s;
            rk[s] += (o0 < rv[s] || (o0 == rv[s] && s2 < myid)) ? 1 : 0;
            rk[s] += (o1 < rv[s] || (o1 == rv[s] && s2 + 64 < myid)) ? 1 : 0;
            rk[s] += (o2 < rv[s] || (o2 == rv[s] && s2 + 128 < myid)) ? 1 : 0;
        }
    }
#pragma unroll
    for (int s = 0; s < 3; s++)
        if (jd[s] >= 0 && rk[s] < Kk) idx_out[(size_t)i * Kk + rk[s]] = jd[s];
}

// ------------------------------------------------- P = X@(W1a-W1b)+b1, Q = X@W1b
__global__ __launch_bounds__(256) void pq_kernel(const float* __restrict__ X,
                                                 const float* __restrict__ W1,
                                                 const float* __restrict__ b1,
                                                 float* __restrict__ P,
                                                 float* __restrict__ Q) {
    __shared__ float xrow[16][Dd];
    const int i0 = blockIdx.x * 16;
    for (int t = threadIdx.x; t < 16 * Dd / 4; t += 256)
        ((float4*)&xrow[0][0])[t] = ((const float4*)(X + (size_t)i0 * Dd))[t];
    __syncthreads();
    const int cc = threadIdx.x & 127;
    const int mat = threadIdx.x >> 7;
    float acc[16];
#pragma unroll
    for (int r = 0; r < 16; r++) acc[r] = 0.f;
    for (int d = 0; d < Dd; d++) {
        float w;
        if (mat == 0) w = W1[d * 128 + cc] - W1[(128 + d) * 128 + cc];
        else          w = W1[(128 + d) * 128 + cc];
#pragma unroll
        for (int r = 0; r < 16; r++) acc[r] = fmaf(xrow[r][d], w, acc[r]);
    }
    if (mat == 0) {
        const float b = b1[cc];
#pragma unroll
        for (int r = 0; r < 16; r++) P[(size_t)(i0 + r) * 128 + cc] = acc[r] + b;
    } else {
#pragma unroll
        for (int r = 0; r < 16; r++) Q[(size_t)(i0 + r) * 128 + cc] = acc[r];
    }
}

// ------------------------------------------- h1 = relu(P + max_k Q[idx]) ----
__global__ __launch_bounds__(128) void h1_kernel(const float* __restrict__ P,
                                                 const float* __restrict__ Q,
                                                 const int* __restrict__ idx,
                                                 float* __restrict__ h1) {
    const int i = blockIdx.x;
    const int c = threadIdx.x;
    __shared__ int jb[Kk];
    if (threadIdx.x < Kk) jb[threadIdx.x] = idx[(size_t)i * Kk + threadIdx.x];
    __syncthreads();
    float m = -INFINITY;
#pragma unroll
    for (int k = 0; k < Kk; k++) m = fmaxf(m, Q[(size_t)jb[k] * 128 + c]);
    h1[(size_t)i * 128 + c] = fmaxf(P[(size_t)i * 128 + c] + m, 0.f);
}

// --------------------------- P2 = h1@(W2a-W2b)+b2, Q2 = h1@W2b (C=10) -------
// LDS-staged W2 (old version gathered W2 with lane-stride-20 addresses ->
// 64 cache lines per load instruction). Thread = one (i, c) pair.
__global__ __launch_bounds__(256) void pq2_kernel(const float* __restrict__ h1,
                                                  const float* __restrict__ W2,
                                                  const float* __restrict__ b2,
                                                  float* __restrict__ P2,
                                                  float* __restrict__ Q2) {
    __shared__ float w2s[2560];        // 256 x 10, linear
    __shared__ float h1s[16][132];     // padded: 4 i-groups land on distinct banks
    const int i0 = blockIdx.x * 16;
    for (int t = threadIdx.x; t < 640; t += 256)
        ((float4*)w2s)[t] = ((const float4*)W2)[t];
    {
        const int r = threadIdx.x >> 4, q = (threadIdx.x & 15) * 8;
        *(float4*)&h1s[r][q]     = *(const float4*)(h1 + (size_t)(i0 + r) * 128 + q);
        *(float4*)&h1s[r][q + 4] = *(const float4*)(h1 + (size_t)(i0 + r) * 128 + q + 4);
    }
    __syncthreads();
    const int il = threadIdx.x >> 4, c = threadIdx.x & 15;
    if (c >= 10) return;
    float pa = 0.f, pb = 0.f;
#pragma unroll 4
    for (int d = 0; d < Dd; d++) {
        const float h = h1s[il][d];
        const float wa = w2s[d * 10 + c];
        const float wb = w2s[(128 + d) * 10 + c];
        pa = fmaf(h, wa - wb, pa);
        pb = fmaf(h, wb, pb);
    }
    P2[(size_t)(i0 + il) * 10 + c] = pa + b2[c];
    Q2[(size_t)(i0 + il) * 10 + c] = pb;
}

// ---------------------------------- out = P2 + max_k Q2[idx] (no relu) ------
__global__ __launch_bounds__(256) void out_kernel(const float* __restrict__ P2,
                                                  const float* __restrict__ Q2,
                                                  const int* __restrict__ idx,
                                                  float* __restrict__ out) {
    const int g = blockIdx.x * 256 + threadIdx.x;
    const int i = g >> 4;
    const int c = g & 15;
    if (c >= 10) return;
    const int* jr = idx + (size_t)i * Kk;
    float m = -INFINITY;
#pragma unroll
    for (int k = 0; k < Kk; k++) m = fmaxf(m, Q2[(size_t)jr[k] * 10 + c]);
    out[(size_t)i * 10 + c] = P2[(size_t)i * 10 + c] + m;
}

extern "C" void kernel_launch(void* const* d_in, const int* in_sizes, int n_in,
                              void* d_out, int out_size, void* d_ws, size_t ws_size,
                              hipStream_t stream) {
    const float* X  = (const float*)d_in[0];
    const float* W1 = (const float*)d_in[1];
    const float* b1 = (const float*)d_in[2];
    const float* W2 = (const float*)d_in[3];
    const float* b2 = (const float*)d_in[4];
    float* out = (float*)d_out;

    char* ws = (char*)d_ws;
    float* sqn = (float*)ws;                                  // 64 KB
    int*   idx = (int*)(ws + (1 << 16));                      // 2 MB
    u16*   Xhi = (u16*)(ws + 2162688);                        // 4 MB
    float* P   = (float*)(ws + 6356992);                      // 8 MB
    float* Q   = P + (size_t)Nn * 128;                        // 8 MB
    float* h1  = Q + (size_t)Nn * 128;                        // 8 MB
    float* P2  = h1 + (size_t)Nn * 128;                       // 640 KB
    float* Q2  = P2 + (size_t)Nn * 10;                        // 640 KB
    // candidate lists alias the P region (consumed by knn_exact BEFORE
    // pq_kernel writes P — same-stream kernels serialize):
    u16* cand    = (u16*)P;                                   // 6 MB
    int* candCnt = (int*)((char*)P + 6 * 1024 * 1024 + 512 * 1024);  // 256 KB

    cvt_kernel<<<Nn * Dd / 4 / 256, 256, 0, stream>>>(X, Xhi);
    sqn_kernel<<<Nn / 4, 256, 0, stream>>>(X, sqn);
    knn_filter<<<256 * JSPLIT, 256, 0, stream>>>(Xhi, sqn, cand, candCnt);
    knn_exact<<<Nn / 4, 256, 0, stream>>>(X, sqn, cand, candCnt, idx);
    pq_kernel<<<Nn / 16, 256, 0, stream>>>(X, W1, b1, P, Q);
    h1_kernel<<<Nn, 128, 0, stream>>>(P, Q, idx, h1);
    pq2_kernel<<<Nn / 16, 256, 0, stream>>>(h1, W2, b2, P2, Q2);
    out_kernel<<<Nn * 16 / 256, 256, 0, stream>>>(P2, Q2, idx, out);
}

// Round 8
// 864.363 us; speedup vs baseline: 2.5185x; 1.0164x over previous
//
#include <hip/hip_runtime.h>
#include <math.h>

#define Nn 16384
#define Dd 128
#define Kk 32
#define JSPLIT 4
#define JCH (Nn / JSPLIT)     // 4096 j per chunk
#define NG (JCH / 16)         // 256 groups of 16 j
#define LCAP2 96              // reservoir slots per row
#define CTRIG 80              // compact when cnt >= CTRIG (burst <= 16 -> max 95)
#define CKEEP 63              // keep cap after streaming compaction
#define FKEEP 48              // candidates written per (row, chunk)
#define BAND 0.4f             // ~7 sigma of hi-bf16 d2 error (validated r6/r7)

typedef unsigned short u16;
typedef short short8 __attribute__((ext_vector_type(8)));
typedef float f32x4 __attribute__((ext_vector_type(4)));
struct __attribute__((aligned(8))) u16x4 { u16 x, y, z, w; };

__device__ __forceinline__ u16 f2bf(float x) {
    unsigned u = __float_as_uint(x);
    unsigned r = u + 0x7FFFu + ((u >> 16) & 1u);   // RN-even
    return (u16)(r >> 16);
}

// ------------------------------------------------------- bf16 convert ------
__global__ __launch_bounds__(256) void cvt_kernel(const float* __restrict__ X,
                                                  u16* __restrict__ hi) {
    const int g = blockIdx.x * 256 + threadIdx.x;
    const float4 v = ((const float4*)X)[g];
    u16x4 h;
    h.x = f2bf(v.x); h.y = f2bf(v.y); h.z = f2bf(v.z); h.w = f2bf(v.w);
    ((u16x4*)hi)[g] = h;
}

// ---------------------------------------------------------------- sqn ------
__global__ __launch_bounds__(256) void sqn_kernel(const float* __restrict__ X,
                                                  float* __restrict__ sqn) {
    const int i = blockIdx.x * 4 + (threadIdx.x >> 6);
    const int lane = threadIdx.x & 63;
    float2 v = *(const float2*)(X + (size_t)i * Dd + lane * 2);
    float s = fmaf(v.x, v.x, v.y * v.y);
#pragma unroll
    for (int o = 32; o > 0; o >>= 1) s += __shfl_down(s, o);
    if (lane == 0) sqn[i] = s;
}

// -------- wave-wide compact/select of one reservoir row (<=95 entries) -----
// Bisect for hi with count(<hi) in [32,48]; keep all < cut = hi+BAND; if over
// capacity, refine cut BY VALUE (drop largest first) -- r6/r7-validated.
__device__ __forceinline__ void compact_row(
    int row, int lane, bool final_pass,
    float (*listv)[LCAP2], u16 (*listj)[LCAP2], float* thrS, int* cnt,
    u16* candOut, int* candCntOut) {
    const int n = cnt[row];
    float v0 = INFINITY, v1 = INFINITY;
    u16 j0 = 0, j1 = 0;
    if (lane < n)      { v0 = listv[row][lane];      j0 = listj[row][lane]; }
    if (lane + 64 < n) { v1 = listv[row][lane + 64]; j1 = listj[row][lane + 64]; }
    float mn = fminf(v0, v1);
    float mx = fmaxf(v0 < INFINITY ? v0 : -INFINITY, v1 < INFINITY ? v1 : -INFINITY);
#pragma unroll
    for (int o = 32; o; o >>= 1) {
        mn = fminf(mn, __shfl_xor(mn, o));
        mx = fmaxf(mx, __shfl_xor(mx, o));
    }
    float lo = mn, hi = mx + 1.0f;
    for (int it = 0; it < 12; it++) {
        const float mid = 0.5f * (lo + hi);
        const int c = __popcll(__ballot(v0 < mid)) + __popcll(__ballot(v1 < mid));
        if (c >= Kk) { hi = mid; if (c <= 48) break; }
        else lo = mid;
    }
    const int cap = final_pass ? FKEEP : CKEEP;
    float cut = hi + BAND;
    int m = __popcll(__ballot(v0 < cut)) + __popcll(__ballot(v1 < cut));
    if (m > cap) {
        float cl = hi, ch = cut;
        for (int it = 0; it < 10; it++) {
            const float mid = 0.5f * (cl + ch);
            const int c = __popcll(__ballot(v0 < mid)) + __popcll(__ballot(v1 < mid));
            if (c <= cap) cl = mid; else ch = mid;
        }
        cut = cl;
        m = __popcll(__ballot(v0 < cut)) + __popcll(__ballot(v1 < cut));
        m = min(m, cap);   // tie-cluster failsafe
    }
    const unsigned long long m0 = __ballot(v0 < cut);
    const unsigned long long m1 = __ballot(v1 < cut);
    const int c0 = __popcll(m0);
    const unsigned long long ltm = (1ull << lane) - 1ull;
    const int p0 = __popcll(m0 & ltm);
    const int p1 = c0 + __popcll(m1 & ltm);
    const bool k0 = ((m0 >> lane) & 1) && (p0 < cap);
    const bool k1 = ((m1 >> lane) & 1) && (p1 < cap);
    if (final_pass) {
        if (k0) candOut[p0] = j0;
        if (k1) candOut[p1] = j1;
        if (lane == 0) *candCntOut = m;
    } else {
        if (k0) { listv[row][p0] = v0; listj[row][p0] = j0; }
        if (k1) { listv[row][p1] = v1; listj[row][p1] = j1; }
        if (lane == 0) { cnt[row] = m; thrS[row] = cut; }
    }
}

// ----------------------------------------------------------- knn filter ----
// 1024 blocks (256 i-tiles x 4 j-chunks) x 256 threads (4 waves, 4 blocks/CU).
// Wave owns 16 i-rows (A-frag resident). B streamed via direct dwordx4 loads,
// register triple-buffered. INSERTS: row counters live in REGISTERS,
// replicated across the owning quad (all 16 lanes see the same ballot so the
// counts stay consistent) -- no LDS atomic, no ds_bpermute, no LDS round trip
// in the hot path. LDS cnt[] only touched on the rare compaction path.
__global__ __launch_bounds__(256, 4) void knn_filter(const u16* __restrict__ Xhi,
                                                     const float* __restrict__ sqn,
                                                     u16* __restrict__ cand,
                                                     int* __restrict__ candCnt) {
    __shared__ float listv[64][LCAP2];   // 24 KB
    __shared__ u16   listj[64][LCAP2];   // 12 KB
    __shared__ float thrS[64];
    __shared__ int   cnt[64];

    const int tid = threadIdx.x;
    const int wave = tid >> 6, lane = tid & 63;
    const int quad = lane >> 4, n16 = lane & 15;
    const int wave16 = wave * 16;
    const int itile = blockIdx.x >> 2, chunk = blockIdx.x & 3;
    const int ibase = itile * 64;
    const int jch0 = chunk * JCH;

    if (tid < 64) { thrS[tid] = INFINITY; cnt[tid] = 0; }
    __syncthreads();   // one-time

    short8 aF[4];
    {
        const u16* arow = Xhi + (size_t)(ibase + wave16 + n16) * Dd + quad * 8;
#pragma unroll
        for (int ks = 0; ks < 4; ks++) aF[ks] = *(const short8*)(arow + ks * 32);
    }
    float thrReg[4] = {INFINITY, INFINITY, INFINITY, INFINITY};
    int cntReg[4] = {0, 0, 0, 0};   // counts for rows wave16+quad*4+r

    const u16* bbase = Xhi + (size_t)(jch0 + n16) * Dd + quad * 8;
    short8 bc[4], b1v[4], b2v[4];
    float sjc, sj1, sj2;
#pragma unroll
    for (int ks = 0; ks < 4; ks++) b1v[ks] = *(const short8*)(bbase + ks * 32);
    sj1 = sqn[jch0 + n16];
#pragma unroll
    for (int ks = 0; ks < 4; ks++) b2v[ks] = *(const short8*)(bbase + 16 * Dd + ks * 32);
    sj2 = sqn[jch0 + 16 + n16];

#pragma unroll 2
    for (int g = 0; g < NG; g++) {
#pragma unroll
        for (int ks = 0; ks < 4; ks++) bc[ks] = b1v[ks];
        sjc = sj1;
#pragma unroll
        for (int ks = 0; ks < 4; ks++) b1v[ks] = b2v[ks];
        sj1 = sj2;
        if (g + 2 < NG) {   // prefetch distance 2
            const u16* nb = bbase + (size_t)(g + 2) * 16 * Dd;
#pragma unroll
            for (int ks = 0; ks < 4; ks++) b2v[ks] = *(const short8*)(nb + ks * 32);
            sj2 = sqn[jch0 + (g + 2) * 16 + n16];
        }
        f32x4 a01 = {0.f, 0.f, 0.f, 0.f}, a23 = {0.f, 0.f, 0.f, 0.f};
        a01 = __builtin_amdgcn_mfma_f32_16x16x32_bf16(aF[0], bc[0], a01, 0, 0, 0);
        a23 = __builtin_amdgcn_mfma_f32_16x16x32_bf16(aF[2], bc[2], a23, 0, 0, 0);
        a01 = __builtin_amdgcn_mfma_f32_16x16x32_bf16(aF[1], bc[1], a01, 0, 0, 0);
        a23 = __builtin_amdgcn_mfma_f32_16x16x32_bf16(aF[3], bc[3], a23, 0, 0, 0);

        const int jj = jch0 + g * 16 + n16;
        float rv[4];
        int pend = 0;
#pragma unroll
        for (int r = 0; r < 4; r++) {
            rv[r] = fmaf(-2.f, a01[r] + a23[r], sjc);
            if (rv[r] < thrReg[r]) pend |= 1 << r;
        }
        if (__any(pend)) {
            bool trig = false;
#pragma unroll
            for (int r = 0; r < 4; r++) {
                const unsigned long long mr = __ballot((pend >> r) & 1);
                const unsigned qm = (unsigned)((mr >> (quad * 16)) & 0xFFFFull);
                if (qm) {   // quad-uniform branch
                    if ((qm >> n16) & 1) {
                        const int row = wave16 + quad * 4 + r;
                        const int pos = cntReg[r] + __popc(qm & ((1u << n16) - 1));
                        listv[row][pos] = rv[r];
                        listj[row][pos] = (u16)jj;
                    }
                    cntReg[r] += __popc(qm);   // quad-consistent
                    trig = trig || (cntReg[r] >= CTRIG);
                }
            }
            if (__any(trig)) {   // rare path: sync reg counts -> LDS, compact
                if (n16 == 0) {
#pragma unroll
                    for (int r = 0; r < 4; r++) cnt[wave16 + quad * 4 + r] = cntReg[r];
                }
                unsigned long long ovm =
                    __ballot(lane < 16 && cnt[wave16 + (lane & 15)] >= CTRIG) & 0xFFFFull;
                while (ovm) {
                    const int rl = (int)(__ffsll(ovm) - 1);
                    ovm &= ovm - 1;
                    compact_row(wave16 + rl, lane, false, listv, listj, thrS, cnt, 0, 0);
                }
#pragma unroll
                for (int r = 0; r < 4; r++) {
                    cntReg[r] = cnt[wave16 + quad * 4 + r];
                    thrReg[r] = thrS[wave16 + quad * 4 + r];
                }
            }
        }
    }

    // final: sync reg counts -> LDS, then per-row select -> global cand lists
    if (n16 == 0) {
#pragma unroll
        for (int r = 0; r < 4; r++) cnt[wave16 + quad * 4 + r] = cntReg[r];
    }
    for (int rl = 0; rl < 16; rl++) {
        const int row = wave16 + rl;
        const int gi = ibase + row;
        u16* co = cand + ((size_t)gi * JSPLIT + chunk) * FKEEP;
        int* cc = candCnt + (size_t)gi * JSPLIT + chunk;
        compact_row(row, lane, true, listv, listj, thrS, cnt, co, cc);
    }
}

// ----------------------------------------------------------- knn exact -----
// 4096 blocks x 256 (wave = one row). Exact fp32 re-rank of the union of the
// 4 per-chunk candidate lists (<=192 slots, 3 per lane).
__global__ __launch_bounds__(256) void knn_exact(const float* __restrict__ X,
                                                 const float* __restrict__ sqn,
                                                 const u16* __restrict__ cand,
                                                 const int* __restrict__ candCnt,
                                                 int* __restrict__ idx_out) {
    __shared__ float xiS[4][Dd];
    const int wave = threadIdx.x >> 6, lane = threadIdx.x & 63;
    const int i = blockIdx.x * 4 + wave;
    *(float2*)&xiS[wave][lane * 2] = *(const float2*)(X + (size_t)i * Dd + lane * 2);
    int cnts[JSPLIT];
#pragma unroll
    for (int k = 0; k < JSPLIT; k++) cnts[k] = candCnt[(size_t)i * JSPLIT + k];
    float rv[3];
    int jd[3];
#pragma unroll
    for (int s = 0; s < 3; s++) {
        const int slot = lane + 64 * s;
        const int k = slot / FKEEP, t = slot - k * FKEEP;
        rv[s] = INFINITY; jd[s] = -1;
        if (t < cnts[k]) {
            const int jj = cand[((size_t)i * JSPLIT + k) * FKEEP + t];
            const float* xj = X + (size_t)jj * Dd;
            float s0 = 0.f, s1 = 0.f, s2 = 0.f, s3 = 0.f;
#pragma unroll
            for (int d = 0; d < Dd; d += 4) {
                const float4 a = *(const float4*)&xiS[wave][d];
                const float4 b = *(const float4*)(xj + d);
                s0 = fmaf(a.x, b.x, s0); s1 = fmaf(a.y, b.y, s1);
                s2 = fmaf(a.z, b.z, s2); s3 = fmaf(a.w, b.w, s3);
            }
            rv[s] = fmaf(-2.f, (s0 + s1) + (s2 + s3), sqn[jj]);
            jd[s] = jj;
        }
    }
    int rk[3] = {0, 0, 0};
    for (int s2 = 0; s2 < 64; s2++) {
        const float o0 = __shfl(rv[0], s2);
        const float o1 = __shfl(rv[1], s2);
        const float o2 = __shfl(rv[2], s2);
#pragma unroll
        for (int s = 0; s < 3; s++) {
            const int myid = lane + 64 * s;
            rk[s] += (o0 < rv[s] || (o0 == rv[s] && s2 < myid)) ? 1 : 0;
            rk[s] += (o1 < rv[s] || (o1 == rv[s] && s2 + 64 < myid)) ? 1 : 0;
            rk[s] += (o2 < rv[s] || (o2 == rv[s] && s2 + 128 < myid)) ? 1 : 0;
        }
    }
#pragma unroll
    for (int s = 0; s < 3; s++)
        if (jd[s] >= 0 && rk[s] < Kk) idx_out[(size_t)i * Kk + rk[s]] = jd[s];
}

// ------------------------------------------------- P = X@(W1a-W1b)+b1, Q = X@W1b
__global__ __launch_bounds__(256) void pq_kernel(const float* __restrict__ X,
                                                 const float* __restrict__ W1,
                                                 const float* __restrict__ b1,
                                                 float* __restrict__ P,
                                                 float* __restrict__ Q) {
    __shared__ float xrow[16][Dd];
    const int i0 = blockIdx.x * 16;
    for (int t = threadIdx.x; t < 16 * Dd / 4; t += 256)
        ((float4*)&xrow[0][0])[t] = ((const float4*)(X + (size_t)i0 * Dd))[t];
    __syncthreads();
    const int cc = threadIdx.x & 127;
    const int mat = threadIdx.x >> 7;
    float acc[16];
#pragma unroll
    for (int r = 0; r < 16; r++) acc[r] = 0.f;
    for (int d = 0; d < Dd; d++) {
        float w;
        if (mat == 0) w = W1[d * 128 + cc] - W1[(128 + d) * 128 + cc];
        else          w = W1[(128 + d) * 128 + cc];
#pragma unroll
        for (int r = 0; r < 16; r++) acc[r] = fmaf(xrow[r][d], w, acc[r]);
    }
    if (mat == 0) {
        const float b = b1[cc];
#pragma unroll
        for (int r = 0; r < 16; r++) P[(size_t)(i0 + r) * 128 + cc] = acc[r] + b;
    } else {
#pragma unroll
        for (int r = 0; r < 16; r++) Q[(size_t)(i0 + r) * 128 + cc] = acc[r];
    }
}

// ------------------------------------------- h1 = relu(P + max_k Q[idx]) ----
__global__ __launch_bounds__(128) void h1_kernel(const float* __restrict__ P,
                                                 const float* __restrict__ Q,
                                                 const int* __restrict__ idx,
                                                 float* __restrict__ h1) {
    const int i = blockIdx.x;
    const int c = threadIdx.x;
    __shared__ int jb[Kk];
    if (threadIdx.x < Kk) jb[threadIdx.x] = idx[(size_t)i * Kk + threadIdx.x];
    __syncthreads();
    float m = -INFINITY;
#pragma unroll
    for (int k = 0; k < Kk; k++) m = fmaxf(m, Q[(size_t)jb[k] * 128 + c]);
    h1[(size_t)i * 128 + c] = fmaxf(P[(size_t)i * 128 + c] + m, 0.f);
}

// --------------------------- P2 = h1@(W2a-W2b)+b2, Q2 = h1@W2b (C=10) -------
__global__ __launch_bounds__(256) void pq2_kernel(const float* __restrict__ h1,
                                                  const float* __restrict__ W2,
                                                  const float* __restrict__ b2,
                                                  float* __restrict__ P2,
                                                  float* __restrict__ Q2) {
    __shared__ float w2s[2560];        // 256 x 10, linear
    __shared__ float h1s[16][132];
    const int i0 = blockIdx.x * 16;
    for (int t = threadIdx.x; t < 640; t += 256)
        ((float4*)w2s)[t] = ((const float4*)W2)[t];
    {
        const int r = threadIdx.x >> 4, q = (threadIdx.x & 15) * 8;
        *(float4*)&h1s[r][q]     = *(const float4*)(h1 + (size_t)(i0 + r) * 128 + q);
        *(float4*)&h1s[r][q + 4] = *(const float4*)(h1 + (size_t)(i0 + r) * 128 + q + 4);
    }
    __syncthreads();
    const int il = threadIdx.x >> 4, c = threadIdx.x & 15;
    if (c >= 10) return;
    float pa = 0.f, pb = 0.f;
#pragma unroll 4
    for (int d = 0; d < Dd; d++) {
        const float h = h1s[il][d];
        const float wa = w2s[d * 10 + c];
        const float wb = w2s[(128 + d) * 10 + c];
        pa = fmaf(h, wa - wb, pa);
        pb = fmaf(h, wb, pb);
    }
    P2[(size_t)(i0 + il) * 10 + c] = pa + b2[c];
    Q2[(size_t)(i0 + il) * 10 + c] = pb;
}

// ---------------------------------- out = P2 + max_k Q2[idx] (no relu) ------
__global__ __launch_bounds__(256) void out_kernel(const float* __restrict__ P2,
                                                  const float* __restrict__ Q2,
                                                  const int* __restrict__ idx,
                                                  float* __restrict__ out) {
    const int g = blockIdx.x * 256 + threadIdx.x;
    const int i = g >> 4;
    const int c = g & 15;
    if (c >= 10) return;
    const int* jr = idx + (size_t)i * Kk;
    float m = -INFINITY;
#pragma unroll
    for (int k = 0; k < Kk; k++) m = fmaxf(m, Q2[(size_t)jr[k] * 10 + c]);
    out[(size_t)i * 10 + c] = P2[(size_t)i * 10 + c] + m;
}

extern "C" void kernel_launch(void* const* d_in, const int* in_sizes, int n_in,
                              void* d_out, int out_size, void* d_ws, size_t ws_size,
                              hipStream_t stream) {
    const float* X  = (const float*)d_in[0];
    const float* W1 = (const float*)d_in[1];
    const float* b1 = (const float*)d_in[2];
    const float* W2 = (const float*)d_in[3];
    const float* b2 = (const float*)d_in[4];
    float* out = (float*)d_out;

    char* ws = (char*)d_ws;
    float* sqn = (float*)ws;                                  // 64 KB
    int*   idx = (int*)(ws + (1 << 16));                      // 2 MB
    u16*   Xhi = (u16*)(ws + 2162688);                        // 4 MB
    float* P   = (float*)(ws + 6356992);                      // 8 MB
    float* Q   = P + (size_t)Nn * 128;                        // 8 MB
    float* h1  = Q + (size_t)Nn * 128;                        // 8 MB
    float* P2  = h1 + (size_t)Nn * 128;                       // 640 KB
    float* Q2  = P2 + (size_t)Nn * 10;                        // 640 KB
    // candidate lists alias the P region (consumed by knn_exact BEFORE
    // pq_kernel writes P — same-stream kernels serialize):
    u16* cand    = (u16*)P;                                   // 6 MB
    int* candCnt = (int*)((char*)P + 6 * 1024 * 1024 + 512 * 1024);  // 256 KB

    cvt_kernel<<<Nn * Dd / 4 / 256, 256, 0, stream>>>(X, Xhi);
    sqn_kernel<<<Nn / 4, 256, 0, stream>>>(X, sqn);
    knn_filter<<<256 * JSPLIT, 256, 0, stream>>>(Xhi, sqn, cand, candCnt);
    knn_exact<<<Nn / 4, 256, 0, stream>>>(X, sqn, cand, candCnt, idx);
    pq_kernel<<<Nn / 16, 256, 0, stream>>>(X, W1, b1, P, Q);
    h1_kernel<<<Nn, 128, 0, stream>>>(P, Q, idx, h1);
    pq2_kernel<<<Nn / 16, 256, 0, stream>>>(h1, W2, b2, P2, Q2);
    out_kernel<<<Nn * 16 / 256, 256, 0, stream>>>(P2, Q2, idx, out);
}

// Round 9
// 769.710 us; speedup vs baseline: 2.8283x; 1.1230x over previous
//
#include <hip/hip_runtime.h>
#include <math.h>

#define Nn 16384
#define Dd 128
#define Kk 32
#define JSPLIT 4
#define JCH (Nn / JSPLIT)     // 4096 j per chunk
#define NG (JCH / 16)         // 256 groups of 16 j per chunk
#define CAP 72                // cand slots per (row, chunk); mean count ~32
#define BAND 0.4f             // 2x bound on hi-bf16 approx rv error (validated r4-r8)
#define ZQ 2.4176f            // Phi^-1(1/128): expected ~128 candidates/row

typedef unsigned short u16;
typedef short short8 __attribute__((ext_vector_type(8)));
typedef float f32x4 __attribute__((ext_vector_type(4)));

__device__ __forceinline__ u16 f2bf(float x) {
    unsigned u = __float_as_uint(x);
    unsigned r = u + 0x7FFFu + ((u >> 16) & 1u);   // RN-even
    return (u16)(r >> 16);
}

// --------------- prep: bf16 convert + sqn + analytic threshold + flag=0 ----
__global__ __launch_bounds__(256) void prep_kernel(const float* __restrict__ X,
                                                   u16* __restrict__ Xhi,
                                                   float* __restrict__ sqn,
                                                   float* __restrict__ thrA,
                                                   int* __restrict__ flagCnt) {
    const int i = blockIdx.x * 4 + (threadIdx.x >> 6);
    const int lane = threadIdx.x & 63;
    const float2 v = *(const float2*)(X + (size_t)i * Dd + lane * 2);
    const unsigned pack = ((unsigned)f2bf(v.y) << 16) | (unsigned)f2bf(v.x);
    *(unsigned*)(Xhi + (size_t)i * Dd + lane * 2) = pack;
    float s = fmaf(v.x, v.x, v.y * v.y);
#pragma unroll
    for (int o = 32; o > 0; o >>= 1) s += __shfl_down(s, o);
    if (lane == 0) {
        sqn[i] = s;
        // rv = sqn_j - 2 xi.xj ~ N(128, 256 + 4*sqn_i); keep rv < thr
        thrA[i] = 128.0f - ZQ * sqrtf(256.0f + 4.0f * s);
    }
    if (blockIdx.x == 0 && threadIdx.x == 0) *flagCnt = 0;
}

// ----------------------------------------------------------- knn filter ----
// 1024 blocks (256 i-tiles x 4 j-chunks) x 256 threads. Wave owns 16 i-rows
// (A-frag resident). STATIC per-row thresholds: no reservoir, no compaction,
// no LDS. Accepts appended straight to global cand lists via ballot ranks +
// quad-replicated register counters. B ping-pong buffered (compile-time
// indices -> no rotation movs). Overflow (cnt > CAP) signaled via raw count.
__global__ __launch_bounds__(256, 4) void knn_filter(const u16* __restrict__ Xhi,
                                                     const float* __restrict__ sqn,
                                                     const float* __restrict__ thrA,
                                                     u16* __restrict__ cand,
                                                     int* __restrict__ candCnt) {
    const int tid = threadIdx.x;
    const int wave = tid >> 6, lane = tid & 63;
    const int quad = lane >> 4, n16 = lane & 15;
    const int wave16 = wave * 16;
    const int itile = blockIdx.x >> 2, chunk = blockIdx.x & 3;
    const int ibase = itile * 64;
    const int jch0 = chunk * JCH;

    short8 aF[4];
    {
        const u16* arow = Xhi + (size_t)(ibase + wave16 + n16) * Dd + quad * 8;
#pragma unroll
        for (int ks = 0; ks < 4; ks++) aF[ks] = *(const short8*)(arow + ks * 32);
    }
    float rvThr[4];
    int cntReg[4] = {0, 0, 0, 0};
#pragma unroll
    for (int r = 0; r < 4; r++) rvThr[r] = thrA[ibase + wave16 + quad * 4 + r];
    // cand base for r=0; rows r differ by a compile-time element offset r*JSPLIT*CAP
    u16* cb = cand + ((size_t)(ibase + wave16 + quad * 4) * JSPLIT + chunk) * CAP;

    const u16* bbase = Xhi + (size_t)(jch0 + n16) * Dd + quad * 8;
    short8 bb[2][4];
    float sj[2];
#pragma unroll
    for (int ks = 0; ks < 4; ks++) bb[0][ks] = *(const short8*)(bbase + ks * 32);
    sj[0] = sqn[jch0 + n16];
#pragma unroll
    for (int ks = 0; ks < 4; ks++) bb[1][ks] = *(const short8*)(bbase + 16 * Dd + ks * 32);
    sj[1] = sqn[jch0 + 16 + n16];

#define PROC(p, gg)                                                            \
    {                                                                          \
        f32x4 a01 = {0.f, 0.f, 0.f, 0.f}, a23 = {0.f, 0.f, 0.f, 0.f};          \
        a01 = __builtin_amdgcn_mfma_f32_16x16x32_bf16(aF[0], bb[p][0], a01, 0, 0, 0); \
        a23 = __builtin_amdgcn_mfma_f32_16x16x32_bf16(aF[2], bb[p][2], a23, 0, 0, 0); \
        a01 = __builtin_amdgcn_mfma_f32_16x16x32_bf16(aF[1], bb[p][1], a01, 0, 0, 0); \
        a23 = __builtin_amdgcn_mfma_f32_16x16x32_bf16(aF[3], bb[p][3], a23, 0, 0, 0); \
        const float sjc = sj[p];                                               \
        if ((gg) + 2 < NG) {                                                   \
            const u16* nb = bbase + (size_t)((gg) + 2) * 16 * Dd;              \
            bb[p][0] = *(const short8*)(nb);                                   \
            bb[p][1] = *(const short8*)(nb + 32);                              \
            bb[p][2] = *(const short8*)(nb + 64);                              \
            bb[p][3] = *(const short8*)(nb + 96);                              \
            sj[p] = sqn[jch0 + ((gg) + 2) * 16 + n16];                         \
        }                                                                      \
        const int jj = jch0 + (gg) * 16 + n16;                                 \
        float rv[4];                                                           \
        rv[0] = fmaf(-2.f, a01[0] + a23[0], sjc);                              \
        rv[1] = fmaf(-2.f, a01[1] + a23[1], sjc);                              \
        rv[2] = fmaf(-2.f, a01[2] + a23[2], sjc);                              \
        rv[3] = fmaf(-2.f, a01[3] + a23[3], sjc);                              \
        _Pragma("unroll")                                                      \
        for (int r = 0; r < 4; r++) {                                          \
            const unsigned long long mr = __ballot(rv[r] < rvThr[r]);          \
            const unsigned qm = (unsigned)((mr >> (quad * 16)) & 0xFFFFull);   \
            if (qm) {                                                          \
                if ((qm >> n16) & 1u) {                                        \
                    const int pos = cntReg[r] + __popc(qm & ((1u << n16) - 1u)); \
                    if (pos < CAP) cb[r * JSPLIT * CAP + pos] = (u16)jj;       \
                }                                                              \
                cntReg[r] += __popc(qm);                                       \
            }                                                                  \
        }                                                                      \
    }

    for (int g = 0; g < NG; g += 2) {
        PROC(0, g)
        PROC(1, g + 1)
    }
#undef PROC

    if (n16 == 0) {
#pragma unroll
        for (int r = 0; r < 4; r++)
            candCnt[((size_t)(ibase + wave16 + quad * 4 + r)) * JSPLIT + chunk] = cntReg[r];
    }
}

// ----------------------------------------------------------- knn exact -----
// 4096 blocks x 256 (wave = one row). Exact fp32 re-rank of the <=288-slot
// candidate union. VERIFIES sufficiency (>=32 exact values below thr-BAND,
// no overflow); failures flagged for knn_cleanup.
__global__ __launch_bounds__(256) void knn_exact(const float* __restrict__ X,
                                                 const float* __restrict__ sqn,
                                                 const float* __restrict__ thrA,
                                                 const u16* __restrict__ cand,
                                                 const int* __restrict__ candCnt,
                                                 int* __restrict__ idx_out,
                                                 int* __restrict__ flagCnt,
                                                 int* __restrict__ flagRows) {
    __shared__ float xiS[4][Dd];
    const int wave = threadIdx.x >> 6, lane = threadIdx.x & 63;
    const int i = blockIdx.x * 4 + wave;
    *(float2*)&xiS[wave][lane * 2] = *(const float2*)(X + (size_t)i * Dd + lane * 2);
    int c0 = candCnt[i * 4 + 0], c1 = candCnt[i * 4 + 1];
    int c2 = candCnt[i * 4 + 2], c3 = candCnt[i * 4 + 3];
    const bool over = (c0 > CAP) || (c1 > CAP) || (c2 > CAP) || (c3 > CAP);
    c0 = min(c0, CAP); c1 = min(c1, CAP); c2 = min(c2, CAP); c3 = min(c3, CAP);
    const int p1 = c0, p2 = p1 + c1, p3 = p2 + c2, M = p3 + c3;
    const float rvT = thrA[i];

    float rv[5];
    int jd[5];
#pragma unroll
    for (int s = 0; s < 5; s++) {
        const int slot = lane + 64 * s;
        rv[s] = INFINITY; jd[s] = -1;
        if (slot < M) {
            const int k = (slot >= p1) + (slot >= p2) + (slot >= p3);
            const int t = slot - (k == 0 ? 0 : (k == 1 ? p1 : (k == 2 ? p2 : p3)));
            const int jj = cand[((size_t)i * JSPLIT + k) * CAP + t];
            const float* xj = X + (size_t)jj * Dd;
            float s0 = 0.f, s1 = 0.f, s2 = 0.f, s3 = 0.f;
#pragma unroll
            for (int d = 0; d < Dd; d += 4) {
                const float4 a = *(const float4*)&xiS[wave][d];
                const float4 b = *(const float4*)(xj + d);
                s0 = fmaf(a.x, b.x, s0); s1 = fmaf(a.y, b.y, s1);
                s2 = fmaf(a.z, b.z, s2); s3 = fmaf(a.w, b.w, s3);
            }
            rv[s] = fmaf(-2.f, (s0 + s1) + (s2 + s3), sqn[jj]);
            jd[s] = jj;
        }
    }
    int good = 0;
#pragma unroll
    for (int s = 0; s < 5; s++) good += __popcll(__ballot(rv[s] < rvT - BAND));
    if (over || good < Kk) {   // insufficient evidence -> exact cleanup path
        if (lane == 0) { const int f = atomicAdd(flagCnt, 1); flagRows[f] = i; }
        return;
    }
    int rk[5] = {0, 0, 0, 0, 0};
    for (int s2 = 0; s2 < 64; s2++) {
        const float o0 = __shfl(rv[0], s2), o1 = __shfl(rv[1], s2), o2 = __shfl(rv[2], s2);
        const float o3 = __shfl(rv[3], s2), o4 = __shfl(rv[4], s2);
#pragma unroll
        for (int s = 0; s < 5; s++) {
            const int myid = lane + 64 * s;
            rk[s] += (o0 < rv[s] || (o0 == rv[s] && s2 < myid));
            rk[s] += (o1 < rv[s] || (o1 == rv[s] && s2 + 64 < myid));
            rk[s] += (o2 < rv[s] || (o2 == rv[s] && s2 + 128 < myid));
            rk[s] += (o3 < rv[s] || (o3 == rv[s] && s2 + 192 < myid));
            rk[s] += (o4 < rv[s] || (o4 == rv[s] && s2 + 256 < myid));
        }
    }
#pragma unroll
    for (int s = 0; s < 5; s++)
        if (jd[s] >= 0 && rk[s] < Kk) idx_out[(size_t)i * Kk + rk[s]] = jd[s];
}

// ----------------------------------------------------------- knn cleanup ---
// Exact fp32 full-scan top-32 for flagged rows (expected: none). Bisection
// threshold select on cached rv values, then collect + rank.
__global__ __launch_bounds__(256) void knn_cleanup(const float* __restrict__ X,
                                                   const float* __restrict__ sqn,
                                                   const int* __restrict__ flagCnt,
                                                   const int* __restrict__ flagRows,
                                                   float* __restrict__ scratch,
                                                   int* __restrict__ idx_out) {
    __shared__ float xi[Dd];
    __shared__ int cntS;
    __shared__ float lv[256];
    __shared__ int lj[256];
    const int tid = threadIdx.x;
    const int lane = tid & 63;
    const int F = *flagCnt;
    float* rvS = scratch + (size_t)blockIdx.x * Nn;
    for (int f = blockIdx.x; f < F; f += gridDim.x) {
        const int i = flagRows[f];
        __syncthreads();
        if (tid < Dd) xi[tid] = X[(size_t)i * Dd + tid];
        __syncthreads();
        for (int j = tid; j < Nn; j += 256) {
            const float* xj = X + (size_t)j * Dd;
            float s0 = 0.f, s1 = 0.f, s2 = 0.f, s3 = 0.f;
#pragma unroll
            for (int d = 0; d < Dd; d += 4) {
                const float4 a = *(const float4*)&xi[d];
                const float4 b = *(const float4*)(xj + d);
                s0 = fmaf(a.x, b.x, s0); s1 = fmaf(a.y, b.y, s1);
                s2 = fmaf(a.z, b.z, s2); s3 = fmaf(a.w, b.w, s3);
            }
            rvS[j] = fmaf(-2.f, (s0 + s1) + (s2 + s3), sqn[j]);
        }
        __syncthreads();
        float lo = -1.0e9f, hi = 1.0e9f, T = 1.0e9f;
        for (int it = 0; it < 48; it++) {
            const float mid = 0.5f * (lo + hi);
            int local = 0;
            for (int j = tid; j < Nn; j += 256) local += (rvS[j] < mid) ? 1 : 0;
#pragma unroll
            for (int o = 32; o > 0; o >>= 1) local += __shfl_down(local, o);
            __syncthreads();
            if (tid == 0) cntS = 0;
            __syncthreads();
            if (lane == 0) atomicAdd(&cntS, local);
            __syncthreads();
            const int c = cntS;
            if (c < Kk) lo = mid;
            else if (c > 200) hi = mid;
            else { T = mid; break; }
        }
        if (T == 1.0e9f) T = hi;
        __syncthreads();
        if (tid == 0) cntS = 0;
        __syncthreads();
        for (int j = tid; j < Nn; j += 256) {
            if (rvS[j] < T) {
                const int p = atomicAdd(&cntS, 1);
                if (p < 256) { lv[p] = rvS[j]; lj[p] = j; }
            }
        }
        __syncthreads();
        const int n = min(cntS, 256);
        if (tid < 64) {
            float v[4]; int jjj[4]; int rk2[4] = {0, 0, 0, 0};
#pragma unroll
            for (int s = 0; s < 4; s++) {
                const int sl = lane + 64 * s;
                v[s] = (sl < n) ? lv[sl] : INFINITY;
                jjj[s] = (sl < n) ? lj[sl] : -1;
            }
            for (int s2 = 0; s2 < 64; s2++) {
                const float o0 = __shfl(v[0], s2), o1 = __shfl(v[1], s2);
                const float o2 = __shfl(v[2], s2), o3 = __shfl(v[3], s2);
#pragma unroll
                for (int s = 0; s < 4; s++) {
                    const int myid = lane + 64 * s;
                    rk2[s] += (o0 < v[s] || (o0 == v[s] && s2 < myid));
                    rk2[s] += (o1 < v[s] || (o1 == v[s] && s2 + 64 < myid));
                    rk2[s] += (o2 < v[s] || (o2 == v[s] && s2 + 128 < myid));
                    rk2[s] += (o3 < v[s] || (o3 == v[s] && s2 + 192 < myid));
                }
            }
#pragma unroll
            for (int s = 0; s < 4; s++)
                if (jjj[s] >= 0 && rk2[s] < Kk) idx_out[(size_t)i * Kk + rk2[s]] = jjj[s];
        }
        __syncthreads();
    }
}

// ------------------------------------------------- P = X@(W1a-W1b)+b1, Q = X@W1b
__global__ __launch_bounds__(256) void pq_kernel(const float* __restrict__ X,
                                                 const float* __restrict__ W1,
                                                 const float* __restrict__ b1,
                                                 float* __restrict__ P,
                                                 float* __restrict__ Q) {
    __shared__ float xrow[16][Dd];
    const int i0 = blockIdx.x * 16;
    for (int t = threadIdx.x; t < 16 * Dd / 4; t += 256)
        ((float4*)&xrow[0][0])[t] = ((const float4*)(X + (size_t)i0 * Dd))[t];
    __syncthreads();
    const int cc = threadIdx.x & 127;
    const int mat = threadIdx.x >> 7;
    float acc[16];
#pragma unroll
    for (int r = 0; r < 16; r++) acc[r] = 0.f;
    for (int d = 0; d < Dd; d++) {
        float w;
        if (mat == 0) w = W1[d * 128 + cc] - W1[(128 + d) * 128 + cc];
        else          w = W1[(128 + d) * 128 + cc];
#pragma unroll
        for (int r = 0; r < 16; r++) acc[r] = fmaf(xrow[r][d], w, acc[r]);
    }
    if (mat == 0) {
        const float b = b1[cc];
#pragma unroll
        for (int r = 0; r < 16; r++) P[(size_t)(i0 + r) * 128 + cc] = acc[r] + b;
    } else {
#pragma unroll
        for (int r = 0; r < 16; r++) Q[(size_t)(i0 + r) * 128 + cc] = acc[r];
    }
}

// ------------------------------------------- h1 = relu(P + max_k Q[idx]) ----
__global__ __launch_bounds__(128) void h1_kernel(const float* __restrict__ P,
                                                 const float* __restrict__ Q,
                                                 const int* __restrict__ idx,
                                                 float* __restrict__ h1) {
    const int i = blockIdx.x;
    const int c = threadIdx.x;
    __shared__ int jb[Kk];
    if (threadIdx.x < Kk) jb[threadIdx.x] = idx[(size_t)i * Kk + threadIdx.x];
    __syncthreads();
    float m = -INFINITY;
#pragma unroll
    for (int k = 0; k < Kk; k++) m = fmaxf(m, Q[(size_t)jb[k] * 128 + c]);
    h1[(size_t)i * 128 + c] = fmaxf(P[(size_t)i * 128 + c] + m, 0.f);
}

// --------------------------- P2 = h1@(W2a-W2b)+b2, Q2 = h1@W2b (C=10) -------
__global__ __launch_bounds__(256) void pq2_kernel(const float* __restrict__ h1,
                                                  const float* __restrict__ W2,
                                                  const float* __restrict__ b2,
                                                  float* __restrict__ P2,
                                                  float* __restrict__ Q2) {
    __shared__ float w2s[2560];        // 256 x 10, linear
    __shared__ float h1s[16][132];
    const int i0 = blockIdx.x * 16;
    for (int t = threadIdx.x; t < 640; t += 256)
        ((float4*)w2s)[t] = ((const float4*)W2)[t];
    {
        const int r = threadIdx.x >> 4, q = (threadIdx.x & 15) * 8;
        *(float4*)&h1s[r][q]     = *(const float4*)(h1 + (size_t)(i0 + r) * 128 + q);
        *(float4*)&h1s[r][q + 4] = *(const float4*)(h1 + (size_t)(i0 + r) * 128 + q + 4);
    }
    __syncthreads();
    const int il = threadIdx.x >> 4, c = threadIdx.x & 15;
    if (c >= 10) return;
    float pa = 0.f, pb = 0.f;
#pragma unroll 4
    for (int d = 0; d < Dd; d++) {
        const float h = h1s[il][d];
        const float wa = w2s[d * 10 + c];
        const float wb = w2s[(128 + d) * 10 + c];
        pa = fmaf(h, wa - wb, pa);
        pb = fmaf(h, wb, pb);
    }
    P2[(size_t)(i0 + il) * 10 + c] = pa + b2[c];
    Q2[(size_t)(i0 + il) * 10 + c] = pb;
}

// ---------------------------------- out = P2 + max_k Q2[idx] (no relu) ------
__global__ __launch_bounds__(256) void out_kernel(const float* __restrict__ P2,
                                                  const float* __restrict__ Q2,
                                                  const int* __restrict__ idx,
                                                  float* __restrict__ out) {
    const int g = blockIdx.x * 256 + threadIdx.x;
    const int i = g >> 4;
    const int c = g & 15;
    if (c >= 10) return;
    const int* jr = idx + (size_t)i * Kk;
    float m = -INFINITY;
#pragma unroll
    for (int k = 0; k < Kk; k++) m = fmaxf(m, Q2[(size_t)jr[k] * 10 + c]);
    out[(size_t)i * 10 + c] = P2[(size_t)i * 10 + c] + m;
}

extern "C" void kernel_launch(void* const* d_in, const int* in_sizes, int n_in,
                              void* d_out, int out_size, void* d_ws, size_t ws_size,
                              hipStream_t stream) {
    const float* X  = (const float*)d_in[0];
    const float* W1 = (const float*)d_in[1];
    const float* b1 = (const float*)d_in[2];
    const float* W2 = (const float*)d_in[3];
    const float* b2 = (const float*)d_in[4];
    float* out = (float*)d_out;

    char* ws = (char*)d_ws;
    float* sqn     = (float*)(ws + 0);            // 64 KB
    float* thrA    = (float*)(ws + 65536);        // 64 KB
    int*   flagCnt = (int*)(ws + 131072);         // 128 B
    int*   flagRows= (int*)(ws + 131200);         // 64 KB
    int*   idx     = (int*)(ws + 262144);         // 2 MB
    u16*   Xhi     = (u16*)(ws + 2359296);        // 4 MB
    float* P       = (float*)(ws + 6553600);      // 8 MB
    float* Q       = P + (size_t)Nn * 128;        // 8 MB
    float* h1      = Q + (size_t)Nn * 128;        // 8 MB
    float* P2      = h1 + (size_t)Nn * 128;       // 640 KB
    float* Q2      = P2 + (size_t)Nn * 10;        // 640 KB
    // cand (9.4 MB) + candCnt alias P/Q (consumed before pq writes them);
    // cleanup scratch (16 MB) aliases the same span (cand dead by then).
    u16* cand    = (u16*)P;
    int* candCnt = (int*)((char*)P + 9437184);    // 256 KB
    float* cleanupScratch = P;                    // 256 blocks x 64 KB = 16 MB

    prep_kernel<<<Nn / 4, 256, 0, stream>>>(X, Xhi, sqn, thrA, flagCnt);
    knn_filter<<<256 * JSPLIT, 256, 0, stream>>>(Xhi, sqn, thrA, cand, candCnt);
    knn_exact<<<Nn / 4, 256, 0, stream>>>(X, sqn, thrA, cand, candCnt, idx, flagCnt, flagRows);
    knn_cleanup<<<256, 256, 0, stream>>>(X, sqn, flagCnt, flagRows, cleanupScratch, idx);
    pq_kernel<<<Nn / 16, 256, 0, stream>>>(X, W1, b1, P, Q);
    h1_kernel<<<Nn, 128, 0, stream>>>(P, Q, idx, h1);
    pq2_kernel<<<Nn / 16, 256, 0, stream>>>(h1, W2, b2, P2, Q2);
    out_kernel<<<Nn * 16 / 256, 256, 0, stream>>>(P2, Q2, idx, out);
}